// Round 1
// baseline (548.825 us; speedup 1.0000x reference)
//
#include <hip/hip_runtime.h>
#include <hip/hip_bf16.h>

// DecoderBlock: B=4, S=2048, D=1024, DFF=4096. fp32 in/out, bf16 MFMA internals.
// Round 1: correctness-first m97-style GEMM (128x128xBK32, 2-phase, linear LDS,
// global_load_lds 16B). Attention via materialized scores + in-place bf16 softmax
// + PV with pre-transposed V. Next rounds: LDS swizzle (T2), 8-phase (T3/T4).

#define Bb 4
#define Ss 2048
#define Dd 1024
#define Ff 4096

typedef __attribute__((ext_vector_type(4))) float f32x4;
typedef __attribute__((ext_vector_type(8))) short bf16x8;
typedef __attribute__((ext_vector_type(8))) unsigned short u16x8;
typedef __attribute__((ext_vector_type(4))) unsigned short u16x4;

__device__ __forceinline__ unsigned short f2bf(float f) {
  unsigned u = __float_as_uint(f);
  u += 0x7FFFu + ((u >> 16) & 1u);
  return (unsigned short)(u >> 16);
}

__device__ __forceinline__ void gload_lds16(const void* g, void* l) {
  __builtin_amdgcn_global_load_lds((const __attribute__((address_space(1))) void*)g,
                                   (__attribute__((address_space(3))) void*)l, 16, 0, 0);
}

// ---------------- elementwise cast fp32 -> bf16 ----------------
__global__ __launch_bounds__(256) void k_cast(const float* __restrict__ in,
                                              unsigned short* __restrict__ out, int n8) {
  int i = blockIdx.x * 256 + threadIdx.x;
  if (i >= n8) return;
  const f32x4* p = (const f32x4*)(in + (size_t)i * 8);
  f32x4 a = p[0], b = p[1];
  u16x8 r;
  r[0] = f2bf(a[0]); r[1] = f2bf(a[1]); r[2] = f2bf(a[2]); r[3] = f2bf(a[3]);
  r[4] = f2bf(b[0]); r[5] = f2bf(b[1]); r[6] = f2bf(b[2]); r[7] = f2bf(b[3]);
  *(u16x8*)(out + (size_t)i * 8) = r;
}

// ---------------- transpose + cast: in[R][C] fp32 -> out[C][R] bf16 ----------------
__global__ __launch_bounds__(256) void k_transpose_cast(const float* __restrict__ in,
                                                        unsigned short* __restrict__ out,
                                                        int R, int C) {
  __shared__ float t[32][33];
  size_t bo = (size_t)blockIdx.z * R * C;
  const float* pin = in + bo;
  unsigned short* pout = out + bo;
  int c0 = blockIdx.x * 32, r0 = blockIdx.y * 32;
  int tx = threadIdx.x, ty = threadIdx.y;
#pragma unroll
  for (int i = 0; i < 4; i++)
    t[ty + i * 8][tx] = pin[(size_t)(r0 + ty + i * 8) * C + c0 + tx];
  __syncthreads();
#pragma unroll
  for (int i = 0; i < 4; i++)
    pout[(size_t)(c0 + ty + i * 8) * R + r0 + tx] = f2bf(t[tx][ty + i * 8]);
}

// ---------------- GEMM: C = A(MxK) * Bt(NxK)^T, bf16 in, fp32 acc ----------------
// EPI: 0 = scores (fp32, *scale; CAUSAL skips fully-masked tiles)
//      1 = plain fp32
//      2 = bias + relu -> bf16
//      3 = bias -> fp32
#define BM 128
#define BN 128
#define BK 32

template <int EPI, bool CAUSAL>
__global__ __launch_bounds__(256) void k_gemm(const unsigned short* __restrict__ A,
                                              const unsigned short* __restrict__ Bt,
                                              float* __restrict__ Cf,
                                              unsigned short* __restrict__ Cb,
                                              const float* __restrict__ bias, int K, int lda,
                                              int ldb, int ldc, long bsA, long bsB, long bsC,
                                              float scale) {
  int i0 = blockIdx.y * BM, j0 = blockIdx.x * BN, bz = blockIdx.z;
  if (EPI == 0 && CAUSAL && j0 > i0 + (BM - 1)) return;  // fully masked tile
  A += (size_t)bz * bsA;
  Bt += (size_t)bz * bsB;

  __shared__ unsigned short sA[2][BM * BK];
  __shared__ unsigned short sB[2][BN * BK];

  int tid = threadIdx.x;
  int w = tid >> 6, lane = tid & 63;
  int wm = w >> 1, wn = w & 1;
  int srow = lane >> 2;        // 0..15 within a 16-row wave-load
  int sk = (lane & 3) * 8;     // k element offset (16B chunk)

  f32x4 acc[4][4];
#pragma unroll
  for (int a = 0; a < 4; a++)
#pragma unroll
    for (int b = 0; b < 4; b++) acc[a][b] = (f32x4){0.f, 0.f, 0.f, 0.f};

  const int nk = K / BK;

  auto stage = [&](int buf, int kt) {
    int k0 = kt * BK;
#pragma unroll
    for (int i = 0; i < 2; i++) {
      int j = w * 2 + i;  // wave-uniform 0..7, 16 rows per wave-load
      int row = j * 16 + srow;
      gload_lds16(A + (size_t)(i0 + row) * lda + k0 + sk, &sA[buf][j * 512]);
      gload_lds16(Bt + (size_t)(j0 + row) * ldb + k0 + sk, &sB[buf][j * 512]);
    }
  };

  stage(0, 0);
  int buf = 0;
  int fr = lane & 15, fg = (lane >> 4) * 8;
  for (int kt = 0; kt < nk; kt++) {
    __syncthreads();  // drains vmcnt: stage(buf) complete, prev compute done
    if (kt + 1 < nk) stage(buf ^ 1, kt + 1);
    bf16x8 af[4], bfr[4];
#pragma unroll
    for (int mi = 0; mi < 4; mi++)
      af[mi] = *(const bf16x8*)&sA[buf][(wm * 64 + mi * 16 + fr) * BK + fg];
#pragma unroll
    for (int ni = 0; ni < 4; ni++)
      bfr[ni] = *(const bf16x8*)&sB[buf][(wn * 64 + ni * 16 + fr) * BK + fg];
#pragma unroll
    for (int mi = 0; mi < 4; mi++)
#pragma unroll
      for (int ni = 0; ni < 4; ni++)
        acc[mi][ni] =
            __builtin_amdgcn_mfma_f32_16x16x32_bf16(af[mi], bfr[ni], acc[mi][ni], 0, 0, 0);
    buf ^= 1;
  }

  // epilogue: D[row=(lane>>4)*4+r][col=lane&15] per 16x16 frag (m89-verified layout)
  size_t cbase = (size_t)bz * bsC;
  int colb = j0 + wn * 64 + (lane & 15);
  int rowb = i0 + wm * 64 + (lane >> 4) * 4;
#pragma unroll
  for (int mi = 0; mi < 4; mi++) {
#pragma unroll
    for (int r = 0; r < 4; r++) {
      size_t ro = cbase + (size_t)(rowb + mi * 16 + r) * ldc;
#pragma unroll
      for (int ni = 0; ni < 4; ni++) {
        int col = colb + ni * 16;
        float v = acc[mi][ni][r];
        if (EPI == 0)
          Cf[ro + col] = v * scale;
        else if (EPI == 1)
          Cf[ro + col] = v;
        else if (EPI == 2)
          Cb[ro + col] = f2bf(fmaxf(v + bias[col], 0.f));
        else
          Cf[ro + col] = v + bias[col];
      }
    }
  }
}

// ---------------- row softmax, fp32 scores -> bf16 P written in place ----------------
template <bool CAUSAL>
__global__ __launch_bounds__(256) void k_softmax(float* __restrict__ scores) {
  int row = blockIdx.x;       // b*S + i
  int i = row & (Ss - 1);
  float* src = scores + (size_t)row * Ss;
  unsigned short* dst = (unsigned short*)src;  // bf16 P in first half of row
  int nv = CAUSAL ? i + 1 : Ss;
  int t = threadIdx.x;
  int w = t >> 6, lane = t & 63;
  float v[8];
  float mx = -1e30f;
#pragma unroll
  for (int k = 0; k < 8; k++) {
    int j = t + k * 256;
    v[k] = (j < nv) ? src[j] : -1e30f;
    mx = fmaxf(mx, v[k]);
  }
#pragma unroll
  for (int o = 32; o; o >>= 1) mx = fmaxf(mx, __shfl_xor(mx, o));
  __shared__ float red[8];
  if (lane == 0) red[w] = mx;
  __syncthreads();
  mx = fmaxf(fmaxf(red[0], red[1]), fmaxf(red[2], red[3]));
  float sum = 0.f;
#pragma unroll
  for (int k = 0; k < 8; k++) {
    int j = t + k * 256;
    float e = (j < nv) ? __expf(v[k] - mx) : 0.f;
    v[k] = e;
    sum += e;
  }
#pragma unroll
  for (int o = 32; o; o >>= 1) sum += __shfl_xor(sum, o);
  if (lane == 0) red[4 + w] = sum;
  __syncthreads();
  sum = red[4] + red[5] + red[6] + red[7];
  float inv = 1.f / sum;
#pragma unroll
  for (int k = 0; k < 8; k++) {
    int j = t + k * 256;
    dst[j] = f2bf(v[k] * inv);  // zeros beyond nv -> PV GEMM sees masked P=0
  }
}

// ---------------- residual add + LayerNorm (one block per row of D=1024) ----------------
__global__ __launch_bounds__(256) void k_add_ln(const float* __restrict__ a,
                                                const float* __restrict__ b,
                                                const float* __restrict__ g,
                                                const float* __restrict__ be,
                                                float* __restrict__ outf,
                                                unsigned short* __restrict__ outb) {
  int row = blockIdx.x;
  size_t o = (size_t)row * Dd;
  int t = threadIdx.x;
  f32x4 xa = *(const f32x4*)(a + o + t * 4);
  f32x4 xb = *(const f32x4*)(b + o + t * 4);
  f32x4 x = xa + xb;
  float s = x[0] + x[1] + x[2] + x[3];
  float q = x[0] * x[0] + x[1] * x[1] + x[2] * x[2] + x[3] * x[3];
  int w = t >> 6, lane = t & 63;
#pragma unroll
  for (int of = 32; of; of >>= 1) {
    s += __shfl_xor(s, of);
    q += __shfl_xor(q, of);
  }
  __shared__ float red[8];
  if (lane == 0) {
    red[w] = s;
    red[4 + w] = q;
  }
  __syncthreads();
  s = red[0] + red[1] + red[2] + red[3];
  q = red[4] + red[5] + red[6] + red[7];
  float mean = s * (1.f / Dd);
  float var = q * (1.f / Dd) - mean * mean;
  float rstd = rsqrtf(var + 1e-5f);
  f32x4 gv = *(const f32x4*)(g + t * 4);
  f32x4 bv = *(const f32x4*)(be + t * 4);
  f32x4 y;
#pragma unroll
  for (int k = 0; k < 4; k++) y[k] = (x[k] - mean) * rstd * gv[k] + bv[k];
  *(f32x4*)(outf + o + t * 4) = y;  // in-place safe: row fully read before write
  if (outb) {
    u16x4 r;
    r[0] = f2bf(y[0]); r[1] = f2bf(y[1]); r[2] = f2bf(y[2]); r[3] = f2bf(y[3]);
    *(u16x4*)(outb + o + t * 4) = r;
  }
}

extern "C" void kernel_launch(void* const* d_in, const int* in_sizes, int n_in, void* d_out,
                              int out_size, void* d_ws, size_t ws_size, hipStream_t stream) {
  (void)in_sizes; (void)n_in; (void)out_size; (void)ws_size;
  const float* y   = (const float*)d_in[0];
  const float* Z   = (const float*)d_in[1];
  const float* w1  = (const float*)d_in[2];
  const float* b1  = (const float*)d_in[3];
  const float* w2  = (const float*)d_in[4];
  const float* b2  = (const float*)d_in[5];
  const float* g1  = (const float*)d_in[6];
  const float* be1 = (const float*)d_in[7];
  const float* g2  = (const float*)d_in[8];
  const float* be2 = (const float*)d_in[9];
  const float* g3  = (const float*)d_in[10];
  const float* be3 = (const float*)d_in[11];
  float* out = (float*)d_out;

  // ws layout (160 MB total):
  //  T    @   0 (16MB)  shared slot: y^T then Z^T (bf16, per-batch DxS)
  //  Zbf  @  16 (16MB)  Z bf16 row-major
  //  ybf  @  32 (16MB)  y bf16, then y1 bf16, then y2 bf16
  //  w1t  @  48 ( 8MB)  w1^T bf16 (DFFxD)
  //  w2t  @  56 ( 8MB)  w2^T bf16 (DxDFF)
  //  sc   @  64 (64MB)  scores fp32 (bf16 P in place); h bf16 aliases after attn
  //  res  @ 128 (32MB)  residual stream fp32 (y1 then y2, in-place LN)
  //  attn/ff scratch = d_out (32MB fp32)
  char* ws = (char*)d_ws;
  const size_t MB = 1024ull * 1024ull;
  unsigned short* T   = (unsigned short*)(ws);
  unsigned short* Zbf = (unsigned short*)(ws + 16 * MB);
  unsigned short* ybf = (unsigned short*)(ws + 32 * MB);
  unsigned short* w1t = (unsigned short*)(ws + 48 * MB);
  unsigned short* w2t = (unsigned short*)(ws + 56 * MB);
  float* sc           = (float*)(ws + 64 * MB);
  unsigned short* h   = (unsigned short*)(ws + 64 * MB);
  float* res          = (float*)(ws + 128 * MB);
  float* attn         = (float*)d_out;

  dim3 b256(256);
  const int n8 = (Bb * Ss * Dd) / 8;
  const float scl = 1.f / 32.f;  // 1/sqrt(D)

  // --- self-attention ---
  k_cast<<<dim3(n8 / 256), b256, 0, stream>>>(y, ybf, n8);
  k_transpose_cast<<<dim3(Dd / 32, Ss / 32, Bb), dim3(32, 8), 0, stream>>>(y, T, Ss, Dd);
  k_gemm<0, true><<<dim3(Ss / BN, Ss / BM, Bb), b256, 0, stream>>>(
      ybf, ybf, sc, nullptr, nullptr, Dd, Dd, Dd, Ss, (long)Ss * Dd, (long)Ss * Dd,
      (long)Ss * Ss, scl);
  k_softmax<true><<<dim3(Bb * Ss), b256, 0, stream>>>(sc);
  k_gemm<1, false><<<dim3(Dd / BN, Ss / BM, Bb), b256, 0, stream>>>(
      (const unsigned short*)sc, T, attn, nullptr, nullptr, Ss, 2 * Ss, Ss, Dd,
      2L * Ss * Ss, (long)Dd * Ss, (long)Ss * Dd, 1.f);
  k_add_ln<<<dim3(Bb * Ss), b256, 0, stream>>>(y, attn, g1, be1, res, ybf);

  // --- cross-attention ---
  k_cast<<<dim3(n8 / 256), b256, 0, stream>>>(Z, Zbf, n8);
  k_transpose_cast<<<dim3(Dd / 32, Ss / 32, Bb), dim3(32, 8), 0, stream>>>(Z, T, Ss, Dd);
  k_gemm<0, false><<<dim3(Ss / BN, Ss / BM, Bb), b256, 0, stream>>>(
      ybf, Zbf, sc, nullptr, nullptr, Dd, Dd, Dd, Ss, (long)Ss * Dd, (long)Ss * Dd,
      (long)Ss * Ss, scl);
  k_softmax<false><<<dim3(Bb * Ss), b256, 0, stream>>>(sc);
  k_gemm<1, false><<<dim3(Dd / BN, Ss / BM, Bb), b256, 0, stream>>>(
      (const unsigned short*)sc, T, attn, nullptr, nullptr, Ss, 2 * Ss, Ss, Dd,
      2L * Ss * Ss, (long)Dd * Ss, (long)Ss * Dd, 1.f);
  k_add_ln<<<dim3(Bb * Ss), b256, 0, stream>>>(res, attn, g2, be2, res, ybf);

  // --- FFN ---
  k_transpose_cast<<<dim3(Ff / 32, Dd / 32, 1), dim3(32, 8), 0, stream>>>(w1, w1t, Dd, Ff);
  k_transpose_cast<<<dim3(Dd / 32, Ff / 32, 1), dim3(32, 8), 0, stream>>>(w2, w2t, Ff, Dd);
  k_gemm<2, false><<<dim3(Ff / BN, (Bb * Ss) / BM, 1), b256, 0, stream>>>(
      ybf, w1t, nullptr, h, b1, Dd, Dd, Dd, Ff, 0L, 0L, 0L, 1.f);
  k_gemm<3, false><<<dim3(Dd / BN, (Bb * Ss) / BM, 1), b256, 0, stream>>>(
      h, w2t, attn, nullptr, b2, Ff, Ff, Ff, Dd, 0L, 0L, 0L, 1.f);
  k_add_ln<<<dim3(Bb * Ss), b256, 0, stream>>>(res, attn, g3, be3, out, nullptr);
}

// Round 2
// 448.123 us; speedup vs baseline: 1.2247x; 1.2247x over previous
//
#include <hip/hip_runtime.h>
#include <hip/hip_bf16.h>

// DecoderBlock: B=4, S=2048, D=1024, DFF=4096. fp32 in/out, bf16 MFMA internals.
// Round 2: 8-phase 256-wide GEMM template (T2 st_16x32 swizzle + T3/T4 counted
// vmcnt + T5 setprio), triangular causal grid, K-capped PV1.

#define Bb 4
#define Ss 2048
#define Dd 1024
#define Ff 4096

typedef __attribute__((ext_vector_type(4))) float f32x4;
typedef __attribute__((ext_vector_type(8))) short bf16x8;
typedef __attribute__((ext_vector_type(8))) unsigned short u16x8;
typedef __attribute__((ext_vector_type(4))) unsigned short u16x4;

__device__ __forceinline__ unsigned short f2bf(float f) {
  unsigned u = __float_as_uint(f);
  u += 0x7FFFu + ((u >> 16) & 1u);
  return (unsigned short)(u >> 16);
}

__device__ __forceinline__ void gload_lds16(const void* g, void* l) {
  __builtin_amdgcn_global_load_lds((const __attribute__((address_space(1))) void*)g,
                                   (__attribute__((address_space(3))) void*)l, 16, 0, 0);
}

// ---------------- elementwise cast fp32 -> bf16 ----------------
__global__ __launch_bounds__(256) void k_cast(const float* __restrict__ in,
                                              unsigned short* __restrict__ out, int n8) {
  int i = blockIdx.x * 256 + threadIdx.x;
  if (i >= n8) return;
  const f32x4* p = (const f32x4*)(in + (size_t)i * 8);
  f32x4 a = p[0], b = p[1];
  u16x8 r;
  r[0] = f2bf(a[0]); r[1] = f2bf(a[1]); r[2] = f2bf(a[2]); r[3] = f2bf(a[3]);
  r[4] = f2bf(b[0]); r[5] = f2bf(b[1]); r[6] = f2bf(b[2]); r[7] = f2bf(b[3]);
  *(u16x8*)(out + (size_t)i * 8) = r;
}

// ---------------- transpose + cast: in[R][C] fp32 -> out[C][R] bf16 ----------------
__global__ __launch_bounds__(256) void k_transpose_cast(const float* __restrict__ in,
                                                        unsigned short* __restrict__ out,
                                                        int R, int C) {
  __shared__ float t[32][33];
  size_t bo = (size_t)blockIdx.z * R * C;
  const float* pin = in + bo;
  unsigned short* pout = out + bo;
  int c0 = blockIdx.x * 32, r0 = blockIdx.y * 32;
  int tx = threadIdx.x, ty = threadIdx.y;
#pragma unroll
  for (int i = 0; i < 4; i++)
    t[ty + i * 8][tx] = pin[(size_t)(r0 + ty + i * 8) * C + c0 + tx];
  __syncthreads();
#pragma unroll
  for (int i = 0; i < 4; i++)
    pout[(size_t)(c0 + ty + i * 8) * R + r0 + tx] = f2bf(t[tx][ty + i * 8]);
}

// =========================================================================
// 8-phase GEMM: C = A(MxK) * Bt(NxK)^T, bf16 in, fp32 acc.
// BNt=256 fixed, BMt in {256,128}. 8 waves: WM=2 x WN=4.
// EPI: 0 scores(*scale fp32) | 1 plain fp32 | 2 bias+relu->bf16 | 3 bias->fp32
// CAUSAL: triangular grid (blockIdx.x = tri index), BMt must equal BNt.
// KCAP: cap K-tiles at i0/64 + BMt/64 (P zero past diagonal -> exact).
// =========================================================================
#define BAR() __builtin_amdgcn_s_barrier()
#define PRIO1() __builtin_amdgcn_s_setprio(1)
#define PRIO0() __builtin_amdgcn_s_setprio(0)

#define LDA8(arr, mh, bo)                                                       \
  {                                                                             \
    _Pragma("unroll") for (int j_ = 0; j_ < QM; ++j_) {                         \
      _Pragma("unroll") for (int kh_ = 0; kh_ < 2; ++kh_) {                     \
        arr[j_][kh_] =                                                          \
            *(const bf16x8*)(lds + (bo) + ((mh)*QM + j_) * 2048 + aof[kh_]);    \
      }                                                                         \
    }                                                                           \
  }

#define LDB8(arr, nh, bo)                                                       \
  {                                                                             \
    _Pragma("unroll") for (int n_ = 0; n_ < 2; ++n_) {                          \
      _Pragma("unroll") for (int kh_ = 0; kh_ < 2; ++kh_) {                     \
        arr[n_][kh_] =                                                          \
            *(const bf16x8*)(lds + (bo) + ((nh)*2 + n_) * 2048 + bof[kh_]);     \
      }                                                                         \
    }                                                                           \
  }

#define MMQ(aarr, barr, mh, nh)                                                 \
  {                                                                             \
    _Pragma("unroll") for (int j_ = 0; j_ < QM; ++j_) {                         \
      _Pragma("unroll") for (int n_ = 0; n_ < 2; ++n_) {                        \
        _Pragma("unroll") for (int kh_ = 0; kh_ < 2; ++kh_) {                   \
          acc[(mh)*QM + j_][(nh)*2 + n_] = __builtin_amdgcn_mfma_f32_16x16x32_bf16( \
              aarr[j_][kh_], barr[n_][kh_], acc[(mh)*QM + j_][(nh)*2 + n_], 0, 0, 0); \
        }                                                                       \
      }                                                                         \
    }                                                                           \
  }

#define VMCNT()                                                                 \
  {                                                                             \
    if constexpr (NVM == 6) asm volatile("s_waitcnt vmcnt(6)" ::: "memory");    \
    else asm volatile("s_waitcnt vmcnt(4)" ::: "memory");                       \
  }

template <int BMt, int EPI, bool CAUSAL, bool KCAP>
__global__ __launch_bounds__(512) void k_gemm8(
    const unsigned short* __restrict__ Ag, const unsigned short* __restrict__ Bg,
    float* __restrict__ Cf, unsigned short* __restrict__ Cb,
    const float* __restrict__ bias, int K, int lda, int ldb, int ldc,
    long bsA, long bsB, long bsC, float scale) {
  constexpr int BNt = 256;
  constexpr int WMS = BMt / 2;      // wave M span (WM=2); WN span = 64
  constexpr int MR = WMS / 16;      // acc M frags: 8 or 4
  constexpr int QM = MR / 2;        // frags per m-half: 4 or 2
  constexpr int LA = BMt / 128;     // loads per A half-tile per thread: 2 or 1
  constexpr int NVM = 2 * LA + 2;   // counted vmcnt
  constexpr int ABYTES = BMt * 128; // one A K-tile buffer (BMt x 64 bf16)
  constexpr int BBYTES = BNt * 128;
  __shared__ alignas(16) char lds[2 * ABYTES + 2 * BBYTES];

  int i0, j0;
  if (CAUSAL) {
    int t = blockIdx.x;
    int ti = (int)((sqrtf(8.f * t + 1.f) - 1.f) * 0.5f);
    while ((ti + 1) * (ti + 2) / 2 <= t) ++ti;
    while (ti * (ti + 1) / 2 > t) --ti;
    i0 = ti * BMt;
    j0 = (t - ti * (ti + 1) / 2) * BNt;
  } else {
    i0 = blockIdx.y * BMt;
    j0 = blockIdx.x * BNt;
  }
  int bz = blockIdx.z;
  Ag += (size_t)bz * bsA;
  Bg += (size_t)bz * bsB;

  int nk = K / 64;
  if (KCAP) {
    int cap = i0 / 64 + BMt / 64;
    nk = nk < cap ? nk : cap;
  }
  const int niter = nk / 2;

  const int tid = threadIdx.x;
  const int w = tid >> 6, lane = tid & 63;
  const int wr = w >> 2, wc = w & 3;

  // ---- staging: linear LDS dest, inverse-st_16x32-swizzled global source ----
  // chunk c = l*8 + w covers 8 rows (1KB). lane: row c*8+lane/8, 16B col lane%8.
  // swizzle: element col ^= ((row>>3)&1)<<4  ->  16B-chunk col ^= (c&1)<<1 = (w&1)<<1.
  const int srow = (w << 3) + (lane >> 3);
  const int bcs = (lane & 7) ^ ((w & 1) << 1);
  const unsigned short* As = Ag + (size_t)(i0 + srow) * lda + bcs * 8;
  const unsigned short* Bs = Bg + (size_t)(j0 + srow) * ldb + bcs * 8;
  char* ldsAw = lds + w * 1024;
  char* ldsBw = lds + 2 * ABYTES + w * 1024;

  auto stA = [&](int kt, int hf) {
    int ks = kt < nk ? kt : nk - 1;
#pragma unroll
    for (int l = 0; l < LA; ++l)
      gload_lds16(As + (size_t)(hf * (BMt / 2) + l * 64) * lda + ks * 64,
                  ldsAw + (kt & 1) * ABYTES + hf * (BMt / 2) * 128 + l * 8192);
  };
  auto stB = [&](int kt, int hf) {
    int ks = kt < nk ? kt : nk - 1;
#pragma unroll
    for (int l = 0; l < 2; ++l)
      gload_lds16(Bs + (size_t)(hf * 128 + l * 64) * ldb + ks * 64,
                  ldsBw + (kt & 1) * BBYTES + hf * 128 * 128 + l * 8192);
  };

  // ---- fragment read offsets (swizzled ds_read) ----
  const int fr = lane & 15, fg = (lane >> 4) << 3;
  const int rA = wr * WMS + fr;
  const int rB = wc * 64 + fr;
  const unsigned xA = ((rA >> 3) & 1) << 4;
  const unsigned xB = ((rB >> 3) & 1) << 4;
  unsigned aof[2], bof[2];
  aof[0] = rA * 128 + (((unsigned)fg ^ xA) << 1);
  aof[1] = rA * 128 + (((unsigned)(32 + fg) ^ xA) << 1);
  bof[0] = 2 * ABYTES + rB * 128 + (((unsigned)fg ^ xB) << 1);
  bof[1] = 2 * ABYTES + rB * 128 + (((unsigned)(32 + fg) ^ xB) << 1);
  constexpr int A0 = 0, A1 = ABYTES, B0 = 0, B1 = BBYTES;  // B ofs already in bof

  f32x4 acc[MR][4];
#pragma unroll
  for (int m = 0; m < MR; ++m)
#pragma unroll
    for (int n = 0; n < 4; ++n) acc[m][n] = (f32x4){0.f, 0.f, 0.f, 0.f};

  bf16x8 a0[QM][2], a1[QM][2], b0[2][2], b1[2][2];

  // ---- prologue: 7 half-tiles, counted drain, barrier ----
  stA(0, 0); stA(0, 1); stB(0, 0); stB(0, 1);
  stA(1, 0); stA(1, 1); stB(1, 0);
  VMCNT();
  BAR();

  for (int t = 0; t < niter; ++t) {
    const int ka = 2 * t + 2, kb = 2 * t + 3;
    // phase 1: read A.mh0+B.nh0 of buf0
    LDA8(a0, 0, A0); LDB8(b0, 0, B0);
    stB(2 * t + 1, 1);
    BAR(); PRIO1(); MMQ(a0, b0, 0, 0); PRIO0(); BAR();
    // phase 2: read A.mh1 (same slot as incoming stage -> pin order)
    LDA8(a1, 1, A0);
    __builtin_amdgcn_sched_barrier(0);
    stA(ka, 0);
    BAR(); PRIO1(); MMQ(a1, b0, 1, 0); PRIO0(); BAR();
    // phase 3: read B.nh1
    LDB8(b1, 1, B0);
    stA(ka, 1);
    BAR(); PRIO1(); MMQ(a1, b1, 1, 1); PRIO0(); BAR();
    // phase 4: no reads; counted vmcnt -> buf1 ready
    stB(ka, 0);
    VMCNT();
    BAR(); PRIO1(); MMQ(a0, b1, 0, 1); PRIO0(); BAR();
    // phase 5
    LDA8(a0, 0, A1); LDB8(b0, 0, B1);
    stB(ka, 1);
    BAR(); PRIO1(); MMQ(a0, b0, 0, 0); PRIO0(); BAR();
    // phase 6
    LDA8(a1, 1, A1);
    __builtin_amdgcn_sched_barrier(0);
    stA(kb, 0);
    BAR(); PRIO1(); MMQ(a1, b0, 1, 0); PRIO0(); BAR();
    // phase 7
    LDB8(b1, 1, B1);
    stA(kb, 1);
    BAR(); PRIO1(); MMQ(a1, b1, 1, 1); PRIO0(); BAR();
    // phase 8: counted vmcnt -> buf0 ready for next iter
    stB(kb, 0);
    VMCNT();
    BAR(); PRIO1(); MMQ(a0, b1, 0, 1); PRIO0(); BAR();
  }

  // ---- epilogue: C[row=(lane>>4)*4+r][col=lane&15] per 16x16 frag ----
  const int colb = j0 + wc * 64 + fr;
  const int rowb = i0 + wr * WMS + ((lane >> 4) << 2);
  const size_t cb = (size_t)bz * bsC;
#pragma unroll
  for (int m = 0; m < MR; ++m) {
#pragma unroll
    for (int r = 0; r < 4; ++r) {
      size_t ro = cb + (size_t)(rowb + m * 16 + r) * ldc;
#pragma unroll
      for (int n = 0; n < 4; ++n) {
        float v = acc[m][n][r];
        int col = colb + n * 16;
        if (EPI == 0) Cf[ro + col] = v * scale;
        else if (EPI == 1) Cf[ro + col] = v;
        else if (EPI == 2) Cb[ro + col] = f2bf(fmaxf(v + bias[col], 0.f));
        else Cf[ro + col] = v + bias[col];
      }
    }
  }
}

// ---------------- row softmax, fp32 scores -> bf16 P written in place ----------------
template <bool CAUSAL>
__global__ __launch_bounds__(256) void k_softmax(float* __restrict__ scores) {
  int row = blockIdx.x;  // b*S + i
  int i = row & (Ss - 1);
  float* src = scores + (size_t)row * Ss;
  unsigned short* dst = (unsigned short*)src;
  int nv = CAUSAL ? i + 1 : Ss;
  int t = threadIdx.x;
  int w = t >> 6, lane = t & 63;
  float v[8];
  float mx = -1e30f;
#pragma unroll
  for (int k = 0; k < 8; k++) {
    int j = t + k * 256;
    v[k] = (j < nv) ? src[j] : -1e30f;
    mx = fmaxf(mx, v[k]);
  }
#pragma unroll
  for (int o = 32; o; o >>= 1) mx = fmaxf(mx, __shfl_xor(mx, o));
  __shared__ float red[8];
  if (lane == 0) red[w] = mx;
  __syncthreads();
  mx = fmaxf(fmaxf(red[0], red[1]), fmaxf(red[2], red[3]));
  float sum = 0.f;
#pragma unroll
  for (int k = 0; k < 8; k++) {
    int j = t + k * 256;
    float e = (j < nv) ? __expf(v[k] - mx) : 0.f;
    v[k] = e;
    sum += e;
  }
#pragma unroll
  for (int o = 32; o; o >>= 1) sum += __shfl_xor(sum, o);
  if (lane == 0) red[4 + w] = sum;
  __syncthreads();
  sum = red[4] + red[5] + red[6] + red[7];
  float inv = 1.f / sum;
#pragma unroll
  for (int k = 0; k < 8; k++) {
    int j = t + k * 256;
    dst[j] = f2bf(v[k] * inv);
  }
}

// ---------------- residual add + LayerNorm ----------------
__global__ __launch_bounds__(256) void k_add_ln(const float* __restrict__ a,
                                                const float* __restrict__ b,
                                                const float* __restrict__ g,
                                                const float* __restrict__ be,
                                                float* __restrict__ outf,
                                                unsigned short* __restrict__ outb) {
  int row = blockIdx.x;
  size_t o = (size_t)row * Dd;
  int t = threadIdx.x;
  f32x4 xa = *(const f32x4*)(a + o + t * 4);
  f32x4 xb = *(const f32x4*)(b + o + t * 4);
  f32x4 x = xa + xb;
  float s = x[0] + x[1] + x[2] + x[3];
  float q = x[0] * x[0] + x[1] * x[1] + x[2] * x[2] + x[3] * x[3];
  int w = t >> 6, lane = t & 63;
#pragma unroll
  for (int of = 32; of; of >>= 1) {
    s += __shfl_xor(s, of);
    q += __shfl_xor(q, of);
  }
  __shared__ float red[8];
  if (lane == 0) {
    red[w] = s;
    red[4 + w] = q;
  }
  __syncthreads();
  s = red[0] + red[1] + red[2] + red[3];
  q = red[4] + red[5] + red[6] + red[7];
  float mean = s * (1.f / Dd);
  float var = q * (1.f / Dd) - mean * mean;
  float rstd = rsqrtf(var + 1e-5f);
  f32x4 gv = *(const f32x4*)(g + t * 4);
  f32x4 bv = *(const f32x4*)(be + t * 4);
  f32x4 y;
#pragma unroll
  for (int k = 0; k < 4; k++) y[k] = (x[k] - mean) * rstd * gv[k] + bv[k];
  *(f32x4*)(outf + o + t * 4) = y;
  if (outb) {
    u16x4 r;
    r[0] = f2bf(y[0]); r[1] = f2bf(y[1]); r[2] = f2bf(y[2]); r[3] = f2bf(y[3]);
    *(u16x4*)(outb + o + t * 4) = r;
  }
}

extern "C" void kernel_launch(void* const* d_in, const int* in_sizes, int n_in, void* d_out,
                              int out_size, void* d_ws, size_t ws_size, hipStream_t stream) {
  (void)in_sizes; (void)n_in; (void)out_size; (void)ws_size;
  const float* y   = (const float*)d_in[0];
  const float* Z   = (const float*)d_in[1];
  const float* w1  = (const float*)d_in[2];
  const float* b1  = (const float*)d_in[3];
  const float* w2  = (const float*)d_in[4];
  const float* b2  = (const float*)d_in[5];
  const float* g1  = (const float*)d_in[6];
  const float* be1 = (const float*)d_in[7];
  const float* g2  = (const float*)d_in[8];
  const float* be2 = (const float*)d_in[9];
  const float* g3  = (const float*)d_in[10];
  const float* be3 = (const float*)d_in[11];
  float* out = (float*)d_out;

  char* ws = (char*)d_ws;
  const size_t MB = 1024ull * 1024ull;
  unsigned short* T   = (unsigned short*)(ws);            // y^T then Z^T (bf16, DxS per batch)
  unsigned short* Zbf = (unsigned short*)(ws + 16 * MB);  // Z bf16
  unsigned short* ybf = (unsigned short*)(ws + 32 * MB);  // y / y1 / y2 bf16
  unsigned short* w1t = (unsigned short*)(ws + 48 * MB);  // w1^T bf16
  unsigned short* w2t = (unsigned short*)(ws + 56 * MB);  // w2^T bf16
  float* sc           = (float*)(ws + 64 * MB);           // scores fp32 / P bf16 in place
  unsigned short* h   = (unsigned short*)(ws + 64 * MB);  // h bf16 aliases sc after attn
  float* res          = (float*)(ws + 128 * MB);          // residual stream fp32
  float* attn         = (float*)d_out;                    // attn / ff scratch

  dim3 b256(256), b512(512);
  const int n8 = (Bb * Ss * Dd) / 8;
  const float scl = 1.f / 32.f;

  // --- self-attention ---
  k_cast<<<dim3(n8 / 256), b256, 0, stream>>>(y, ybf, n8);
  k_transpose_cast<<<dim3(Dd / 32, Ss / 32, Bb), dim3(32, 8), 0, stream>>>(y, T, Ss, Dd);
  k_gemm8<256, 0, true, false><<<dim3(36, 1, Bb), b512, 0, stream>>>(
      ybf, ybf, sc, nullptr, nullptr, Dd, Dd, Dd, Ss, (long)Ss * Dd, (long)Ss * Dd,
      (long)Ss * Ss, scl);
  k_softmax<true><<<dim3(Bb * Ss), b256, 0, stream>>>(sc);
  k_gemm8<128, 1, false, true><<<dim3(Dd / 256, Ss / 128, Bb), b512, 0, stream>>>(
      (const unsigned short*)sc, T, attn, nullptr, nullptr, Ss, 2 * Ss, Ss, Dd,
      2L * Ss * Ss, (long)Dd * Ss, (long)Ss * Dd, 1.f);
  k_add_ln<<<dim3(Bb * Ss), b256, 0, stream>>>(y, attn, g1, be1, res, ybf);

  // --- cross-attention ---
  k_cast<<<dim3(n8 / 256), b256, 0, stream>>>(Z, Zbf, n8);
  k_transpose_cast<<<dim3(Dd / 32, Ss / 32, Bb), dim3(32, 8), 0, stream>>>(Z, T, Ss, Dd);
  k_gemm8<256, 0, false, false><<<dim3(Ss / 256, Ss / 256, Bb), b512, 0, stream>>>(
      ybf, Zbf, sc, nullptr, nullptr, Dd, Dd, Dd, Ss, (long)Ss * Dd, (long)Ss * Dd,
      (long)Ss * Ss, scl);
  k_softmax<false><<<dim3(Bb * Ss), b256, 0, stream>>>(sc);
  k_gemm8<128, 1, false, false><<<dim3(Dd / 256, Ss / 128, Bb), b512, 0, stream>>>(
      (const unsigned short*)sc, T, attn, nullptr, nullptr, Ss, 2 * Ss, Ss, Dd,
      2L * Ss * Ss, (long)Dd * Ss, (long)Ss * Dd, 1.f);
  k_add_ln<<<dim3(Bb * Ss), b256, 0, stream>>>(res, attn, g2, be2, res, ybf);

  // --- FFN ---
  k_transpose_cast<<<dim3(Ff / 32, Dd / 32, 1), dim3(32, 8), 0, stream>>>(w1, w1t, Dd, Ff);
  k_transpose_cast<<<dim3(Dd / 32, Ff / 32, 1), dim3(32, 8), 0, stream>>>(w2, w2t, Ff, Dd);
  k_gemm8<256, 2, false, false><<<dim3(Ff / 256, (Bb * Ss) / 256, 1), b512, 0, stream>>>(
      ybf, w1t, nullptr, h, b1, Dd, Dd, Dd, Ff, 0L, 0L, 0L, 1.f);
  k_gemm8<128, 3, false, false><<<dim3(Dd / 256, (Bb * Ss) / 128, 1), b512, 0, stream>>>(
      h, w2t, attn, nullptr, b2, Ff, Ff, Ff, Dd, 0L, 0L, 0L, 1.f);
  k_add_ln<<<dim3(Bb * Ss), b256, 0, stream>>>(res, attn, g3, be3, out, nullptr);
}

// Round 3
// 406.519 us; speedup vs baseline: 1.3501x; 1.1023x over previous
//
#include <hip/hip_runtime.h>
#include <hip/hip_bf16.h>

// DecoderBlock: B=4, S=2048, D=1024, DFF=4096. fp32 in/out, bf16 MFMA internals.
// Round 3: proper 3-bit LDS chunk swizzle (chunk ^= row&7) both-sides (rule #21),
// race-free stage placement (stage >=1 barrier after target's last read),
// T1 bijective XCD remap, cast fused into transpose.

#define Bb 4
#define Ss 2048
#define Dd 1024
#define Ff 4096

typedef __attribute__((ext_vector_type(4))) float f32x4;
typedef __attribute__((ext_vector_type(8))) short bf16x8;
typedef __attribute__((ext_vector_type(8))) unsigned short u16x8;
typedef __attribute__((ext_vector_type(4))) unsigned short u16x4;

__device__ __forceinline__ unsigned short f2bf(float f) {
  unsigned u = __float_as_uint(f);
  u += 0x7FFFu + ((u >> 16) & 1u);
  return (unsigned short)(u >> 16);
}

__device__ __forceinline__ void gload_lds16(const void* g, void* l) {
  __builtin_amdgcn_global_load_lds((const __attribute__((address_space(1))) void*)g,
                                   (__attribute__((address_space(3))) void*)l, 16, 0, 0);
}

// bijective XCD-chunk remap (m204): consecutive outputs land on one XCD
__device__ __forceinline__ int xcd8(int orig, int n) {
  int q = n >> 3, r = n & 7;
  int x = orig & 7;
  int base = x < r ? x * (q + 1) : r * (q + 1) + (x - r) * q;
  return base + (orig >> 3);
}

// ---------------- transpose+cast: in[R][C] fp32 -> outT[C][R] bf16 (+opt outR[R][C] bf16) --
__global__ __launch_bounds__(256) void k_transpose_cast(const float* __restrict__ in,
                                                        unsigned short* __restrict__ outT,
                                                        unsigned short* __restrict__ outR,
                                                        int R, int C) {
  __shared__ float t[32][33];
  size_t bo = (size_t)blockIdx.z * R * C;
  const float* pin = in + bo;
  unsigned short* poutT = outT + bo;
  unsigned short* poutR = outR ? outR + bo : nullptr;
  int c0 = blockIdx.x * 32, r0 = blockIdx.y * 32;
  int tx = threadIdx.x, ty = threadIdx.y;
#pragma unroll
  for (int i = 0; i < 4; i++) {
    float v = pin[(size_t)(r0 + ty + i * 8) * C + c0 + tx];
    t[ty + i * 8][tx] = v;
    if (poutR) poutR[(size_t)(r0 + ty + i * 8) * C + c0 + tx] = f2bf(v);
  }
  __syncthreads();
#pragma unroll
  for (int i = 0; i < 4; i++)
    poutT[(size_t)(c0 + ty + i * 8) * R + r0 + tx] = f2bf(t[tx][ty + i * 8]);
}

// =========================================================================
// 8-phase GEMM: C = A(MxK) * Bt(NxK)^T, bf16 in, fp32 acc.
// BNt=256 fixed, BMt in {256,128}. 8 waves: WM=2 x WN=4. LDS tile rows are
// 128B (64 bf16); 16B chunk c of row r holds logical chunk c^(r&7) (3-bit
// swizzle -> conflict-free ds_read_b128). Staging: linear LDS dest +
// inverse-swizzled global source. Stage placement: each half-tile staged
// >=1 barrier after its slot's last ds_read (no cross-wave WAR window).
// vmcnt gates (instr-counted): BMt=256 -> 6, BMt=128 -> 4, at phases 4/8.
// =========================================================================
#define BAR() __builtin_amdgcn_s_barrier()
#define PRIO1() __builtin_amdgcn_s_setprio(1)
#define PRIO0() __builtin_amdgcn_s_setprio(0)

#define LDA8(arr, mh, bo)                                                       \
  {                                                                             \
    _Pragma("unroll") for (int j_ = 0; j_ < QM; ++j_) {                         \
      _Pragma("unroll") for (int kh_ = 0; kh_ < 2; ++kh_) {                     \
        arr[j_][kh_] =                                                          \
            *(const bf16x8*)(lds + (bo) + ((mh)*QM + j_) * 2048 + aof[kh_]);    \
      }                                                                         \
    }                                                                           \
  }

#define LDB8(arr, nh, bo)                                                       \
  {                                                                             \
    _Pragma("unroll") for (int n_ = 0; n_ < 2; ++n_) {                          \
      _Pragma("unroll") for (int kh_ = 0; kh_ < 2; ++kh_) {                     \
        arr[n_][kh_] =                                                          \
            *(const bf16x8*)(lds + (bo) + ((nh)*2 + n_) * 2048 + bof[kh_]);     \
      }                                                                         \
    }                                                                           \
  }

#define MMQ(aarr, barr, mh, nh)                                                 \
  {                                                                             \
    _Pragma("unroll") for (int j_ = 0; j_ < QM; ++j_) {                         \
      _Pragma("unroll") for (int n_ = 0; n_ < 2; ++n_) {                        \
        _Pragma("unroll") for (int kh_ = 0; kh_ < 2; ++kh_) {                   \
          acc[(mh)*QM + j_][(nh)*2 + n_] = __builtin_amdgcn_mfma_f32_16x16x32_bf16( \
              aarr[j_][kh_], barr[n_][kh_], acc[(mh)*QM + j_][(nh)*2 + n_], 0, 0, 0); \
        }                                                                       \
      }                                                                         \
    }                                                                           \
  }

#define VMCNT()                                                                 \
  {                                                                             \
    if constexpr (NVM == 6) asm volatile("s_waitcnt vmcnt(6)" ::: "memory");    \
    else asm volatile("s_waitcnt vmcnt(4)" ::: "memory");                       \
  }

template <int BMt, int EPI, bool CAUSAL, bool KCAP>
__global__ __launch_bounds__(512) void k_gemm8(
    const unsigned short* __restrict__ Ag, const unsigned short* __restrict__ Bg,
    float* __restrict__ Cf, unsigned short* __restrict__ Cb,
    const float* __restrict__ bias, int K, int lda, int ldb, int ldc,
    long bsA, long bsB, long bsC, float scale) {
  constexpr int BNt = 256;
  constexpr int WMS = BMt / 2;      // wave M span (WM=2); WN span = 64
  constexpr int MR = WMS / 16;      // acc M frags: 8 or 4
  constexpr int QM = MR / 2;        // frags per m-half: 4 or 2
  constexpr int LA = BMt / 128;     // gload instrs per A half-tile: 2 or 1
  constexpr int NVM = 2 * LA + 2;   // counted vmcnt (instrs of 3 half-tiles... see gates)
  constexpr int ABYTES = BMt * 128;
  constexpr int BBYTES = BNt * 128;
  __shared__ alignas(16) char lds[2 * ABYTES + 2 * BBYTES];

  int i0, j0;
  if (CAUSAL) {
    int t = xcd8(blockIdx.x, gridDim.x);
    int ti = (int)((sqrtf(8.f * t + 1.f) - 1.f) * 0.5f);
    while ((ti + 1) * (ti + 2) / 2 <= t) ++ti;
    while (ti * (ti + 1) / 2 > t) --ti;
    i0 = ti * BMt;
    j0 = (t - ti * (ti + 1) / 2) * BNt;
  } else {
    int lin = xcd8(blockIdx.y * gridDim.x + blockIdx.x, gridDim.x * gridDim.y);
    i0 = (lin / gridDim.x) * BMt;
    j0 = (lin % gridDim.x) * BNt;
  }
  int bz = blockIdx.z;
  Ag += (size_t)bz * bsA;
  Bg += (size_t)bz * bsB;

  int nk = K / 64;
  if (KCAP) {
    int cap = i0 / 64 + BMt / 64;
    nk = nk < cap ? nk : cap;
  }
  const int niter = nk / 2;

  const int tid = threadIdx.x;
  const int w = tid >> 6, lane = tid & 63;
  const int wr = w >> 2, wc = w & 3;

  // ---- staging: linear LDS dest; global source pre-applies inverse swizzle.
  // wave w writes 1KB = rows w*8..w*8+7 (+64*l, +hf*BMt/2); lane -> physical
  // (row = w*8 + lane>>3, chunk = lane&7). Physical chunk p at row r must hold
  // logical chunk p^(r&7) -> source chunk = (lane&7)^(lane>>3).
  const int srow = (w << 3) + (lane >> 3);
  const int bcs = (lane & 7) ^ (lane >> 3);
  const unsigned short* As = Ag + (size_t)(i0 + srow) * lda + bcs * 8;
  const unsigned short* Bs = Bg + (size_t)(j0 + srow) * ldb + bcs * 8;
  char* ldsAw = lds + w * 1024;
  char* ldsBw = lds + 2 * ABYTES + w * 1024;

  auto stA = [&](int kt, int hf) {
    int ks = kt < nk ? kt : nk - 1;
#pragma unroll
    for (int l = 0; l < LA; ++l)
      gload_lds16(As + (size_t)(hf * (BMt / 2) + l * 64) * lda + ks * 64,
                  ldsAw + (kt & 1) * ABYTES + hf * (BMt / 2) * 128 + l * 8192);
  };
  auto stB = [&](int kt, int hf) {
    int ks = kt < nk ? kt : nk - 1;
#pragma unroll
    for (int l = 0; l < 2; ++l)
      gload_lds16(Bs + (size_t)(hf * 128 + l * 64) * ldb + ks * 64,
                  ldsBw + (kt & 1) * BBYTES + hf * 128 * 128 + l * 8192);
  };

  // ---- swizzled ds_read offsets: logical chunk lc at row r lives at lc^(r&7) ----
  const int fr = lane & 15, kq = lane >> 4;  // kq = logical 16B chunk 0..3 (kh adds 4)
  const int rA = wr * WMS + fr;
  const int rB = wc * 64 + fr;
  unsigned aof[2], bof[2];
  aof[0] = rA * 128 + ((kq ^ (rA & 7)) << 4);
  aof[1] = rA * 128 + (((kq + 4) ^ (rA & 7)) << 4);
  bof[0] = 2 * ABYTES + rB * 128 + ((kq ^ (rB & 7)) << 4);
  bof[1] = 2 * ABYTES + rB * 128 + (((kq + 4) ^ (rB & 7)) << 4);
  constexpr int A0 = 0, A1 = ABYTES, B0 = 0, B1 = BBYTES;

  f32x4 acc[MR][4];
#pragma unroll
  for (int m = 0; m < MR; ++m)
#pragma unroll
    for (int n = 0; n < 4; ++n) acc[m][n] = (f32x4){0.f, 0.f, 0.f, 0.f};

  bf16x8 a0[QM][2], a1[QM][2], b0[2][2], b1[2][2];

  // ---- prologue: 7 half-tiles; drain tile-0 (vmcnt leaves tile-1's 3 halves) ----
  stA(0, 0); stA(0, 1); stB(0, 0); stB(0, 1);
  stA(1, 0); stA(1, 1); stB(1, 0);
  VMCNT();
  BAR();

  // Reads per slot: A buf: phases 1(a0)+2(a1); B buf: phases 1(b0)+3(b1) [+4 phases
  // for buf1]. Stages placed >=1 barrier after the slot's last read.
  for (int t = 0; t < niter; ++t) {
    const int ka = 2 * t + 2, kb = 2 * t + 3;
    // phase 1
    LDA8(a0, 0, A0); LDB8(b0, 0, B0);
    stB(2 * t + 1, 1);                    // buf1-B-h1: last read prev ph7
    BAR(); PRIO1(); MMQ(a0, b0, 0, 0); PRIO0(); BAR();
    // phase 2
    LDA8(a1, 1, A0);
    BAR(); PRIO1(); MMQ(a1, b0, 1, 0); PRIO0(); BAR();
    // phase 3
    LDB8(b1, 1, B0);
    stA(ka, 0);                           // buf0-A: reads done ph2
    BAR(); PRIO1(); MMQ(a1, b1, 1, 1); PRIO0(); BAR();
    // phase 4: gate tile-(2t+1) before buf1 reads
    stA(ka, 1); stB(ka, 0);               // buf0-B-h0: reads done ph3
    VMCNT();
    BAR(); PRIO1(); MMQ(a0, b1, 0, 1); PRIO0(); BAR();
    // phase 5
    LDA8(a0, 0, A1); LDB8(b0, 0, B1);
    stB(ka, 1);                           // buf0-B-h1: reads done ph3
    BAR(); PRIO1(); MMQ(a0, b0, 0, 0); PRIO0(); BAR();
    // phase 6
    LDA8(a1, 1, A1);
    BAR(); PRIO1(); MMQ(a1, b0, 1, 0); PRIO0(); BAR();
    // phase 7
    LDB8(b1, 1, B1);
    stA(kb, 0);                           // buf1-A: reads done ph6
    BAR(); PRIO1(); MMQ(a1, b1, 1, 1); PRIO0(); BAR();
    // phase 8: gate tile-ka before next-iter buf0 reads
    stA(kb, 1); stB(kb, 0);               // buf1-B-h0: reads done ph7
    VMCNT();
    BAR(); PRIO1(); MMQ(a0, b1, 0, 1); PRIO0(); BAR();
  }

  // ---- epilogue: C[row=(lane>>4)*4+r][col=lane&15] per 16x16 frag ----
  const int colb = j0 + wc * 64 + fr;
  const int rowb = i0 + wr * WMS + (kq << 2);
  const size_t cb = (size_t)bz * bsC;
#pragma unroll
  for (int m = 0; m < MR; ++m) {
#pragma unroll
    for (int r = 0; r < 4; ++r) {
      size_t ro = cb + (size_t)(rowb + m * 16 + r) * ldc;
#pragma unroll
      for (int n = 0; n < 4; ++n) {
        float v = acc[m][n][r];
        int col = colb + n * 16;
        if (EPI == 0) Cf[ro + col] = v * scale;
        else if (EPI == 1) Cf[ro + col] = v;
        else if (EPI == 2) Cb[ro + col] = f2bf(fmaxf(v + bias[col], 0.f));
        else Cf[ro + col] = v + bias[col];
      }
    }
  }
}

// ---------------- row softmax, fp32 scores -> bf16 P written in place ----------------
template <bool CAUSAL>
__global__ __launch_bounds__(256) void k_softmax(float* __restrict__ scores) {
  int row = blockIdx.x;  // b*S + i
  int i = row & (Ss - 1);
  float* src = scores + (size_t)row * Ss;
  unsigned short* dst = (unsigned short*)src;
  int nv = CAUSAL ? i + 1 : Ss;
  int t = threadIdx.x;
  int w = t >> 6, lane = t & 63;
  float v[8];
  float mx = -1e30f;
#pragma unroll
  for (int k = 0; k < 8; k++) {
    int j = t + k * 256;
    v[k] = (j < nv) ? src[j] : -1e30f;
    mx = fmaxf(mx, v[k]);
  }
#pragma unroll
  for (int o = 32; o; o >>= 1) mx = fmaxf(mx, __shfl_xor(mx, o));
  __shared__ float red[8];
  if (lane == 0) red[w] = mx;
  __syncthreads();
  mx = fmaxf(fmaxf(red[0], red[1]), fmaxf(red[2], red[3]));
  float sum = 0.f;
#pragma unroll
  for (int k = 0; k < 8; k++) {
    int j = t + k * 256;
    float e = (j < nv) ? __expf(v[k] - mx) : 0.f;
    v[k] = e;
    sum += e;
  }
#pragma unroll
  for (int o = 32; o; o >>= 1) sum += __shfl_xor(sum, o);
  if (lane == 0) red[4 + w] = sum;
  __syncthreads();
  sum = red[4] + red[5] + red[6] + red[7];
  float inv = 1.f / sum;
#pragma unroll
  for (int k = 0; k < 8; k++) {
    int j = t + k * 256;
    dst[j] = f2bf(v[k] * inv);
  }
}

// ---------------- residual add + LayerNorm ----------------
__global__ __launch_bounds__(256) void k_add_ln(const float* __restrict__ a,
                                                const float* __restrict__ b,
                                                const float* __restrict__ g,
                                                const float* __restrict__ be,
                                                float* __restrict__ outf,
                                                unsigned short* __restrict__ outb) {
  int row = blockIdx.x;
  size_t o = (size_t)row * Dd;
  int t = threadIdx.x;
  f32x4 xa = *(const f32x4*)(a + o + t * 4);
  f32x4 xb = *(const f32x4*)(b + o + t * 4);
  f32x4 x = xa + xb;
  float s = x[0] + x[1] + x[2] + x[3];
  float q = x[0] * x[0] + x[1] * x[1] + x[2] * x[2] + x[3] * x[3];
  int w = t >> 6, lane = t & 63;
#pragma unroll
  for (int of = 32; of; of >>= 1) {
    s += __shfl_xor(s, of);
    q += __shfl_xor(q, of);
  }
  __shared__ float red[8];
  if (lane == 0) {
    red[w] = s;
    red[4 + w] = q;
  }
  __syncthreads();
  s = red[0] + red[1] + red[2] + red[3];
  q = red[4] + red[5] + red[6] + red[7];
  float mean = s * (1.f / Dd);
  float var = q * (1.f / Dd) - mean * mean;
  float rstd = rsqrtf(var + 1e-5f);
  f32x4 gv = *(const f32x4*)(g + t * 4);
  f32x4 bv = *(const f32x4*)(be + t * 4);
  f32x4 y;
#pragma unroll
  for (int k = 0; k < 4; k++) y[k] = (x[k] - mean) * rstd * gv[k] + bv[k];
  *(f32x4*)(outf + o + t * 4) = y;
  if (outb) {
    u16x4 r;
    r[0] = f2bf(y[0]); r[1] = f2bf(y[1]); r[2] = f2bf(y[2]); r[3] = f2bf(y[3]);
    *(u16x4*)(outb + o + t * 4) = r;
  }
}

extern "C" void kernel_launch(void* const* d_in, const int* in_sizes, int n_in, void* d_out,
                              int out_size, void* d_ws, size_t ws_size, hipStream_t stream) {
  (void)in_sizes; (void)n_in; (void)out_size; (void)ws_size;
  const float* y   = (const float*)d_in[0];
  const float* Z   = (const float*)d_in[1];
  const float* w1  = (const float*)d_in[2];
  const float* b1  = (const float*)d_in[3];
  const float* w2  = (const float*)d_in[4];
  const float* b2  = (const float*)d_in[5];
  const float* g1  = (const float*)d_in[6];
  const float* be1 = (const float*)d_in[7];
  const float* g2  = (const float*)d_in[8];
  const float* be2 = (const float*)d_in[9];
  const float* g3  = (const float*)d_in[10];
  const float* be3 = (const float*)d_in[11];
  float* out = (float*)d_out;

  char* ws = (char*)d_ws;
  const size_t MB = 1024ull * 1024ull;
  unsigned short* T   = (unsigned short*)(ws);            // y^T then Z^T (bf16, DxS per batch)
  unsigned short* Zbf = (unsigned short*)(ws + 16 * MB);  // Z bf16
  unsigned short* ybf = (unsigned short*)(ws + 32 * MB);  // y / y1 / y2 bf16
  unsigned short* w1t = (unsigned short*)(ws + 48 * MB);  // w1^T bf16
  unsigned short* w2t = (unsigned short*)(ws + 56 * MB);  // w2^T bf16
  float* sc           = (float*)(ws + 64 * MB);           // scores fp32 / P bf16 in place
  unsigned short* h   = (unsigned short*)(ws + 64 * MB);  // h bf16 aliases sc after attn
  float* res          = (float*)(ws + 128 * MB);          // residual stream fp32
  float* attn         = (float*)d_out;                    // attn / ff scratch

  dim3 b256(256), b512(512);
  const float scl = 1.f / 32.f;

  // --- self-attention ---
  k_transpose_cast<<<dim3(Dd / 32, Ss / 32, Bb), dim3(32, 8), 0, stream>>>(y, T, ybf, Ss, Dd);
  k_gemm8<256, 0, true, false><<<dim3(36, 1, Bb), b512, 0, stream>>>(
      ybf, ybf, sc, nullptr, nullptr, Dd, Dd, Dd, Ss, (long)Ss * Dd, (long)Ss * Dd,
      (long)Ss * Ss, scl);
  k_softmax<true><<<dim3(Bb * Ss), b256, 0, stream>>>(sc);
  k_gemm8<128, 1, false, true><<<dim3(Dd / 256, Ss / 128, Bb), b512, 0, stream>>>(
      (const unsigned short*)sc, T, attn, nullptr, nullptr, Ss, 2 * Ss, Ss, Dd,
      2L * Ss * Ss, (long)Dd * Ss, (long)Ss * Dd, 1.f);
  k_add_ln<<<dim3(Bb * Ss), b256, 0, stream>>>(y, attn, g1, be1, res, ybf);

  // --- cross-attention ---
  k_transpose_cast<<<dim3(Dd / 32, Ss / 32, Bb), dim3(32, 8), 0, stream>>>(Z, T, Zbf, Ss, Dd);
  k_gemm8<256, 0, false, false><<<dim3(Ss / 256, Ss / 256, Bb), b512, 0, stream>>>(
      ybf, Zbf, sc, nullptr, nullptr, Dd, Dd, Dd, Ss, (long)Ss * Dd, (long)Ss * Dd,
      (long)Ss * Ss, scl);
  k_softmax<false><<<dim3(Bb * Ss), b256, 0, stream>>>(sc);
  k_gemm8<128, 1, false, false><<<dim3(Dd / 256, Ss / 128, Bb), b512, 0, stream>>>(
      (const unsigned short*)sc, T, attn, nullptr, nullptr, Ss, 2 * Ss, Ss, Dd,
      2L * Ss * Ss, (long)Dd * Ss, (long)Ss * Dd, 1.f);
  k_add_ln<<<dim3(Bb * Ss), b256, 0, stream>>>(res, attn, g2, be2, res, ybf);

  // --- FFN ---
  k_transpose_cast<<<dim3(Ff / 32, Dd / 32, 1), dim3(32, 8), 0, stream>>>(w1, w1t, nullptr, Dd, Ff);
  k_transpose_cast<<<dim3(Dd / 32, Ff / 32, 1), dim3(32, 8), 0, stream>>>(w2, w2t, nullptr, Ff, Dd);
  k_gemm8<256, 2, false, false><<<dim3(Ff / 256, (Bb * Ss) / 256, 1), b512, 0, stream>>>(
      ybf, w1t, nullptr, h, b1, Dd, Dd, Dd, Ff, 0L, 0L, 0L, 1.f);
  k_gemm8<128, 3, false, false><<<dim3(Dd / 256, (Bb * Ss) / 128, 1), b512, 0, stream>>>(
      h, w2t, attn, nullptr, b2, Ff, Ff, Ff, Dd, 0L, 0L, 0L, 1.f);
  k_add_ln<<<dim3(Bb * Ss), b256, 0, stream>>>(res, attn, g3, be3, out, nullptr);
}

// Round 4
// 403.422 us; speedup vs baseline: 1.3604x; 1.0077x over previous
//
#include <hip/hip_runtime.h>
#include <hip/hip_bf16.h>

// DecoderBlock: B=4, S=2048, D=1024, DFF=4096. fp32 in/out, bf16 MFMA internals.
// Round 4: k_gemm4 (BMt=128, 4-phase, 16 MFMA/phase) for N=1024 GEMMs;
// explicit lgkmcnt(0)+sched_barrier(0) after barrier (m201 parity); bf16 scores.

#define Bb 4
#define Ss 2048
#define Dd 1024
#define Ff 4096

typedef __attribute__((ext_vector_type(4))) float f32x4;
typedef __attribute__((ext_vector_type(8))) short bf16x8;
typedef __attribute__((ext_vector_type(8))) unsigned short u16x8;
typedef __attribute__((ext_vector_type(4))) unsigned short u16x4;

__device__ __forceinline__ unsigned short f2bf(float f) {
  unsigned u = __float_as_uint(f);
  u += 0x7FFFu + ((u >> 16) & 1u);
  return (unsigned short)(u >> 16);
}
__device__ __forceinline__ float bf2f(unsigned short h) {
  return __uint_as_float(((unsigned)h) << 16);
}

__device__ __forceinline__ void gload_lds16(const void* g, void* l) {
  __builtin_amdgcn_global_load_lds((const __attribute__((address_space(1))) void*)g,
                                   (__attribute__((address_space(3))) void*)l, 16, 0, 0);
}

__device__ __forceinline__ int xcd8(int orig, int n) {
  int q = n >> 3, r = n & 7;
  int x = orig & 7;
  int base = x < r ? x * (q + 1) : r * (q + 1) + (x - r) * q;
  return base + (orig >> 3);
}

// ---------------- transpose+cast: in[R][C] fp32 -> outT[C][R] bf16 (+opt outR bf16) ----
__global__ __launch_bounds__(256) void k_transpose_cast(const float* __restrict__ in,
                                                        unsigned short* __restrict__ outT,
                                                        unsigned short* __restrict__ outR,
                                                        int R, int C) {
  __shared__ float t[32][33];
  size_t bo = (size_t)blockIdx.z * R * C;
  const float* pin = in + bo;
  unsigned short* poutT = outT + bo;
  unsigned short* poutR = outR ? outR + bo : nullptr;
  int c0 = blockIdx.x * 32, r0 = blockIdx.y * 32;
  int tx = threadIdx.x, ty = threadIdx.y;
#pragma unroll
  for (int i = 0; i < 4; i++) {
    float v = pin[(size_t)(r0 + ty + i * 8) * C + c0 + tx];
    t[ty + i * 8][tx] = v;
    if (poutR) poutR[(size_t)(r0 + ty + i * 8) * C + c0 + tx] = f2bf(v);
  }
  __syncthreads();
#pragma unroll
  for (int i = 0; i < 4; i++)
    poutT[(size_t)(c0 + ty + i * 8) * R + r0 + tx] = f2bf(t[tx][ty + i * 8]);
}

// ---- shared GEMM machinery --------------------------------------------------
// EPI: 0 = *scale -> bf16 (scores) | 1 = plain fp32 | 2 = bias+relu -> bf16 | 3 = bias fp32
#define BAR() __builtin_amdgcn_s_barrier()
#define PRIO1() __builtin_amdgcn_s_setprio(1)
#define PRIO0() __builtin_amdgcn_s_setprio(0)
#define LGKM0()                                          \
  {                                                      \
    asm volatile("s_waitcnt lgkmcnt(0)" ::: "memory");   \
    __builtin_amdgcn_sched_barrier(0);                   \
  }

#define LDA8(arr, mh, bo)                                                       \
  {                                                                             \
    _Pragma("unroll") for (int j_ = 0; j_ < QM; ++j_) {                         \
      _Pragma("unroll") for (int kh_ = 0; kh_ < 2; ++kh_) {                     \
        arr[j_][kh_] =                                                          \
            *(const bf16x8*)(lds + (bo) + ((mh)*QM + j_) * 2048 + aof[kh_]);    \
      }                                                                         \
    }                                                                           \
  }

#define LDB8(arr, nh, bo)                                                       \
  {                                                                             \
    _Pragma("unroll") for (int n_ = 0; n_ < 2; ++n_) {                          \
      _Pragma("unroll") for (int kh_ = 0; kh_ < 2; ++kh_) {                     \
        arr[n_][kh_] =                                                          \
            *(const bf16x8*)(lds + (bo) + ((nh)*2 + n_) * 2048 + bof[kh_]);     \
      }                                                                         \
    }                                                                           \
  }

#define MMQ(aarr, barr, mh, nh)                                                 \
  {                                                                             \
    _Pragma("unroll") for (int j_ = 0; j_ < QM; ++j_) {                         \
      _Pragma("unroll") for (int n_ = 0; n_ < 2; ++n_) {                        \
        _Pragma("unroll") for (int kh_ = 0; kh_ < 2; ++kh_) {                   \
          acc[(mh)*QM + j_][(nh)*2 + n_] = __builtin_amdgcn_mfma_f32_16x16x32_bf16( \
              aarr[j_][kh_], barr[n_][kh_], acc[(mh)*QM + j_][(nh)*2 + n_], 0, 0, 0); \
        }                                                                       \
      }                                                                         \
    }                                                                           \
  }

#define EPILOGUE(MR_, WMS_)                                                     \
  {                                                                             \
    const int colb = j0 + wc * 64 + fr;                                         \
    const int rowb = i0 + wr * (WMS_) + (kq << 2);                              \
    const size_t cb = (size_t)bz * bsC;                                         \
    _Pragma("unroll") for (int m = 0; m < (MR_); ++m) {                         \
      _Pragma("unroll") for (int r = 0; r < 4; ++r) {                           \
        size_t ro = cb + (size_t)(rowb + m * 16 + r) * ldc;                     \
        _Pragma("unroll") for (int n = 0; n < 4; ++n) {                         \
          float v = acc[m][n][r];                                               \
          int col = colb + n * 16;                                              \
          if (EPI == 0) Cb[ro + col] = f2bf(v * scale);                         \
          else if (EPI == 1) Cf[ro + col] = v;                                  \
          else if (EPI == 2) Cb[ro + col] = f2bf(fmaxf(v + bias[col], 0.f));    \
          else Cf[ro + col] = v + bias[col];                                    \
        }                                                                       \
      }                                                                         \
    }                                                                           \
  }

// ========================= k_gemm8: BMt=256, 8-phase =========================
template <int EPI, bool CAUSAL>
__global__ __launch_bounds__(512) void k_gemm8(
    const unsigned short* __restrict__ Ag, const unsigned short* __restrict__ Bg,
    float* __restrict__ Cf, unsigned short* __restrict__ Cb,
    const float* __restrict__ bias, int K, int lda, int ldb, int ldc,
    long bsA, long bsB, long bsC, float scale) {
  constexpr int QM = 4;             // frags per m-half (MR=8)
  constexpr int ABYTES = 32768, BBYTES = 32768;
  __shared__ alignas(16) char lds[2 * ABYTES + 2 * BBYTES];

  int i0, j0;
  if (CAUSAL) {
    int t = xcd8(blockIdx.x, gridDim.x);
    int ti = (int)((sqrtf(8.f * t + 1.f) - 1.f) * 0.5f);
    while ((ti + 1) * (ti + 2) / 2 <= t) ++ti;
    while (ti * (ti + 1) / 2 > t) --ti;
    i0 = ti * 256;
    j0 = (t - ti * (ti + 1) / 2) * 256;
  } else {
    int lin = xcd8(blockIdx.y * gridDim.x + blockIdx.x, gridDim.x * gridDim.y);
    i0 = (lin / gridDim.x) * 256;
    j0 = (lin % gridDim.x) * 256;
  }
  int bz = blockIdx.z;
  Ag += (size_t)bz * bsA;
  Bg += (size_t)bz * bsB;

  const int nk = K / 64;
  const int niter = nk / 2;

  const int tid = threadIdx.x;
  const int w = tid >> 6, lane = tid & 63;
  const int wr = w >> 2, wc = w & 3;

  const int srow = (w << 3) + (lane >> 3);
  const int bcs = (lane & 7) ^ (lane >> 3);
  const unsigned short* As = Ag + (size_t)(i0 + srow) * lda + bcs * 8;
  const unsigned short* Bs = Bg + (size_t)(j0 + srow) * ldb + bcs * 8;
  char* ldsAw = lds + w * 1024;
  char* ldsBw = lds + 2 * ABYTES + w * 1024;

  auto stA = [&](int kt, int hf) {
    int ks = kt < nk ? kt : nk - 1;
#pragma unroll
    for (int l = 0; l < 2; ++l)
      gload_lds16(As + (size_t)(hf * 128 + l * 64) * lda + ks * 64,
                  ldsAw + (kt & 1) * ABYTES + hf * 128 * 128 + l * 8192);
  };
  auto stB = [&](int kt, int hf) {
    int ks = kt < nk ? kt : nk - 1;
#pragma unroll
    for (int l = 0; l < 2; ++l)
      gload_lds16(Bs + (size_t)(hf * 128 + l * 64) * ldb + ks * 64,
                  ldsBw + (kt & 1) * BBYTES + hf * 128 * 128 + l * 8192);
  };

  const int fr = lane & 15, kq = lane >> 4;
  const int rA = wr * 128 + fr;
  const int rB = wc * 64 + fr;
  unsigned aof[2], bof[2];
  aof[0] = rA * 128 + ((kq ^ (rA & 7)) << 4);
  aof[1] = rA * 128 + (((kq + 4) ^ (rA & 7)) << 4);
  bof[0] = 2 * ABYTES + rB * 128 + ((kq ^ (rB & 7)) << 4);
  bof[1] = 2 * ABYTES + rB * 128 + (((kq + 4) ^ (rB & 7)) << 4);
  constexpr int A0 = 0, A1 = ABYTES, B0 = 0, B1 = BBYTES;

  f32x4 acc[8][4];
#pragma unroll
  for (int m = 0; m < 8; ++m)
#pragma unroll
    for (int n = 0; n < 4; ++n) acc[m][n] = (f32x4){0.f, 0.f, 0.f, 0.f};

  bf16x8 a0[QM][2], a1[QM][2], b0[2][2], b1[2][2];

  stA(0, 0); stA(0, 1); stB(0, 0); stB(0, 1);
  stA(1, 0); stA(1, 1); stB(1, 0);
  asm volatile("s_waitcnt vmcnt(6)" ::: "memory");
  BAR();

  for (int t = 0; t < niter; ++t) {
    const int ka = 2 * t + 2, kb = 2 * t + 3;
    LDA8(a0, 0, A0); LDB8(b0, 0, B0);
    stB(2 * t + 1, 1);
    BAR(); LGKM0(); PRIO1(); MMQ(a0, b0, 0, 0); PRIO0(); BAR();
    LDA8(a1, 1, A0);
    BAR(); LGKM0(); PRIO1(); MMQ(a1, b0, 1, 0); PRIO0(); BAR();
    LDB8(b1, 1, B0);
    stA(ka, 0);
    BAR(); LGKM0(); PRIO1(); MMQ(a1, b1, 1, 1); PRIO0(); BAR();
    stA(ka, 1); stB(ka, 0);
    asm volatile("s_waitcnt vmcnt(6)" ::: "memory");
    BAR(); PRIO1(); MMQ(a0, b1, 0, 1); PRIO0(); BAR();
    LDA8(a0, 0, A1); LDB8(b0, 0, B1);
    stB(ka, 1);
    BAR(); LGKM0(); PRIO1(); MMQ(a0, b0, 0, 0); PRIO0(); BAR();
    LDA8(a1, 1, A1);
    BAR(); LGKM0(); PRIO1(); MMQ(a1, b0, 1, 0); PRIO0(); BAR();
    LDB8(b1, 1, B1);
    stA(kb, 0);
    BAR(); LGKM0(); PRIO1(); MMQ(a1, b1, 1, 1); PRIO0(); BAR();
    stA(kb, 1); stB(kb, 0);
    asm volatile("s_waitcnt vmcnt(6)" ::: "memory");
    BAR(); PRIO1(); MMQ(a0, b1, 0, 1); PRIO0(); BAR();
  }
  EPILOGUE(8, 128)
}

// ========================= k_gemm4: BMt=128, 4-phase =========================
template <int EPI, bool KCAP>
__global__ __launch_bounds__(512) void k_gemm4(
    const unsigned short* __restrict__ Ag, const unsigned short* __restrict__ Bg,
    float* __restrict__ Cf, unsigned short* __restrict__ Cb,
    const float* __restrict__ bias, int K, int lda, int ldb, int ldc,
    long bsA, long bsB, long bsC, float scale) {
  constexpr int QM = 4;             // all 4 M-frags in one group (mh=0)
  constexpr int ABYTES = 16384, BBYTES = 32768;
  __shared__ alignas(16) char lds[2 * ABYTES + 2 * BBYTES];

  int lin = xcd8(blockIdx.y * gridDim.x + blockIdx.x, gridDim.x * gridDim.y);
  int i0 = (lin / gridDim.x) * 128;
  int j0 = (lin % gridDim.x) * 256;
  int bz = blockIdx.z;
  Ag += (size_t)bz * bsA;
  Bg += (size_t)bz * bsB;

  int nk = K / 64;
  if (KCAP) {
    int cap = i0 / 64 + 2;
    nk = nk < cap ? nk : cap;
  }
  const int niter = nk / 2;

  const int tid = threadIdx.x;
  const int w = tid >> 6, lane = tid & 63;
  const int wr = w >> 2, wc = w & 3;

  const int srow = (w << 3) + (lane >> 3);
  const int bcs = (lane & 7) ^ (lane >> 3);
  const unsigned short* As = Ag + (size_t)(i0 + srow) * lda + bcs * 8;
  const unsigned short* Bs = Bg + (size_t)(j0 + srow) * ldb + bcs * 8;
  char* ldsAw = lds + w * 1024;
  char* ldsBw = lds + 2 * ABYTES + w * 1024;

  auto stA2 = [&](int kt) {  // both halves (2 instrs)
    int ks = kt < nk ? kt : nk - 1;
#pragma unroll
    for (int hf = 0; hf < 2; ++hf)
      gload_lds16(As + (size_t)(hf * 64) * lda + ks * 64,
                  ldsAw + (kt & 1) * ABYTES + hf * 64 * 128);
  };
  auto stB2 = [&](int kt) {  // both halves (4 instrs)
    int ks = kt < nk ? kt : nk - 1;
#pragma unroll
    for (int hf = 0; hf < 2; ++hf)
#pragma unroll
      for (int l = 0; l < 2; ++l)
        gload_lds16(Bs + (size_t)(hf * 128 + l * 64) * ldb + ks * 64,
                    ldsBw + (kt & 1) * BBYTES + hf * 128 * 128 + l * 8192);
  };

  const int fr = lane & 15, kq = lane >> 4;
  const int rA = wr * 64 + fr;
  const int rB = wc * 64 + fr;
  unsigned aof[2], bof[2];
  aof[0] = rA * 128 + ((kq ^ (rA & 7)) << 4);
  aof[1] = rA * 128 + (((kq + 4) ^ (rA & 7)) << 4);
  bof[0] = 2 * ABYTES + rB * 128 + ((kq ^ (rB & 7)) << 4);
  bof[1] = 2 * ABYTES + rB * 128 + (((kq + 4) ^ (rB & 7)) << 4);
  constexpr int A0 = 0, A1 = ABYTES, B0 = 0, B1 = BBYTES;

  f32x4 acc[4][4];
#pragma unroll
  for (int m = 0; m < 4; ++m)
#pragma unroll
    for (int n = 0; n < 4; ++n) acc[m][n] = (f32x4){0.f, 0.f, 0.f, 0.f};

  bf16x8 a[QM][2], b0[2][2], b1[2][2];

  // prologue: tile0 (6 instr) + A(1) (2 instr); drain tile0
  stA2(0); stB2(0); stA2(1);
  asm volatile("s_waitcnt vmcnt(2)" ::: "memory");
  BAR();

  for (int t = 0; t < niter; ++t) {
    const int ka = 2 * t + 2, kb = 2 * t + 3;
    // ph1: buf0 A-all + B.nh0; stage B(2t+1) both halves (buf1-B last read prev ph4)
    LDA8(a, 0, A0); LDB8(b0, 0, B0);
    stB2(2 * t + 1);
    BAR(); LGKM0(); PRIO1(); MMQ(a, b0, 0, 0); PRIO0(); BAR();
    // ph2: buf0 B.nh1; stage A(ka) (buf0-A last read ph1); gate tile(2t+1)
    LDB8(b1, 1, B0);
    stA2(ka);
    asm volatile("s_waitcnt vmcnt(2)" ::: "memory");
    BAR(); LGKM0(); PRIO1(); MMQ(a, b1, 0, 1); PRIO0(); BAR();
    // ph3: buf1 A-all + B.nh0; stage B(ka) (buf0-B last read ph2)
    LDA8(a, 0, A1); LDB8(b0, 0, B1);
    stB2(ka);
    BAR(); LGKM0(); PRIO1(); MMQ(a, b0, 0, 0); PRIO0(); BAR();
    // ph4: buf1 B.nh1; stage A(kb) (buf1-A last read ph3); gate tile-ka
    LDB8(b1, 1, B1);
    stA2(kb);
    asm volatile("s_waitcnt vmcnt(2)" ::: "memory");
    BAR(); LGKM0(); PRIO1(); MMQ(a, b1, 0, 1); PRIO0(); BAR();
  }
  EPILOGUE(4, 64)
}

// ---------------- row softmax, bf16 scores -> bf16 P in place ----------------
template <bool CAUSAL>
__global__ __launch_bounds__(256) void k_softmax(unsigned short* __restrict__ scores) {
  int row = blockIdx.x;  // b*S + i
  int i = row & (Ss - 1);
  unsigned short* src = scores + (size_t)row * Ss;
  int nv = CAUSAL ? i + 1 : Ss;
  int t = threadIdx.x;
  int w = t >> 6, lane = t & 63;
  u16x8 raw = *(const u16x8*)(src + t * 8);
  float v[8];
  float mx = -1e30f;
#pragma unroll
  for (int k = 0; k < 8; k++) {
    int j = t * 8 + k;
    v[k] = (j < nv) ? bf2f(raw[k]) : -1e30f;
    mx = fmaxf(mx, v[k]);
  }
#pragma unroll
  for (int o = 32; o; o >>= 1) mx = fmaxf(mx, __shfl_xor(mx, o));
  __shared__ float red[8];
  if (lane == 0) red[w] = mx;
  __syncthreads();
  mx = fmaxf(fmaxf(red[0], red[1]), fmaxf(red[2], red[3]));
  float sum = 0.f;
#pragma unroll
  for (int k = 0; k < 8; k++) {
    int j = t * 8 + k;
    float e = (j < nv) ? __expf(v[k] - mx) : 0.f;
    v[k] = e;
    sum += e;
  }
#pragma unroll
  for (int o = 32; o; o >>= 1) sum += __shfl_xor(sum, o);
  if (lane == 0) red[4 + w] = sum;
  __syncthreads();
  sum = red[4] + red[5] + red[6] + red[7];
  float inv = 1.f / sum;
  u16x8 r;
#pragma unroll
  for (int k = 0; k < 8; k++) r[k] = f2bf(v[k] * inv);
  *(u16x8*)(src + t * 8) = r;
}

// ---------------- residual add + LayerNorm ----------------
__global__ __launch_bounds__(256) void k_add_ln(const float* __restrict__ a,
                                                const float* __restrict__ b,
                                                const float* __restrict__ g,
                                                const float* __restrict__ be,
                                                float* __restrict__ outf,
                                                unsigned short* __restrict__ outb) {
  int row = blockIdx.x;
  size_t o = (size_t)row * Dd;
  int t = threadIdx.x;
  f32x4 xa = *(const f32x4*)(a + o + t * 4);
  f32x4 xb = *(const f32x4*)(b + o + t * 4);
  f32x4 x = xa + xb;
  float s = x[0] + x[1] + x[2] + x[3];
  float q = x[0] * x[0] + x[1] * x[1] + x[2] * x[2] + x[3] * x[3];
  int w = t >> 6, lane = t & 63;
#pragma unroll
  for (int of = 32; of; of >>= 1) {
    s += __shfl_xor(s, of);
    q += __shfl_xor(q, of);
  }
  __shared__ float red[8];
  if (lane == 0) {
    red[w] = s;
    red[4 + w] = q;
  }
  __syncthreads();
  s = red[0] + red[1] + red[2] + red[3];
  q = red[4] + red[5] + red[6] + red[7];
  float mean = s * (1.f / Dd);
  float var = q * (1.f / Dd) - mean * mean;
  float rstd = rsqrtf(var + 1e-5f);
  f32x4 gv = *(const f32x4*)(g + t * 4);
  f32x4 bv = *(const f32x4*)(be + t * 4);
  f32x4 y;
#pragma unroll
  for (int k = 0; k < 4; k++) y[k] = (x[k] - mean) * rstd * gv[k] + bv[k];
  *(f32x4*)(outf + o + t * 4) = y;
  if (outb) {
    u16x4 r;
    r[0] = f2bf(y[0]); r[1] = f2bf(y[1]); r[2] = f2bf(y[2]); r[3] = f2bf(y[3]);
    *(u16x4*)(outb + o + t * 4) = r;
  }
}

extern "C" void kernel_launch(void* const* d_in, const int* in_sizes, int n_in, void* d_out,
                              int out_size, void* d_ws, size_t ws_size, hipStream_t stream) {
  (void)in_sizes; (void)n_in; (void)out_size; (void)ws_size;
  const float* y   = (const float*)d_in[0];
  const float* Z   = (const float*)d_in[1];
  const float* w1  = (const float*)d_in[2];
  const float* b1  = (const float*)d_in[3];
  const float* w2  = (const float*)d_in[4];
  const float* b2  = (const float*)d_in[5];
  const float* g1  = (const float*)d_in[6];
  const float* be1 = (const float*)d_in[7];
  const float* g2  = (const float*)d_in[8];
  const float* be2 = (const float*)d_in[9];
  const float* g3  = (const float*)d_in[10];
  const float* be3 = (const float*)d_in[11];
  float* out = (float*)d_out;

  char* ws = (char*)d_ws;
  const size_t MB = 1024ull * 1024ull;
  unsigned short* T   = (unsigned short*)(ws);            // y^T then Z^T (bf16, DxS per batch)
  unsigned short* Zbf = (unsigned short*)(ws + 16 * MB);  // Z bf16
  unsigned short* ybf = (unsigned short*)(ws + 32 * MB);  // y / y1 / y2 bf16
  unsigned short* w1t = (unsigned short*)(ws + 48 * MB);  // w1^T bf16
  unsigned short* w2t = (unsigned short*)(ws + 56 * MB);  // w2^T bf16
  unsigned short* sc  = (unsigned short*)(ws + 64 * MB);  // scores/P bf16 (32MB)
  unsigned short* h   = (unsigned short*)(ws + 64 * MB);  // h bf16 (64MB) aliases dead sc
  float* res          = (float*)(ws + 128 * MB);          // residual stream fp32
  float* attn         = (float*)d_out;                    // attn / ff scratch

  dim3 b256(256), b512(512);
  const float scl = 1.f / 32.f;

  // --- self-attention ---
  k_transpose_cast<<<dim3(Dd / 32, Ss / 32, Bb), dim3(32, 8), 0, stream>>>(y, T, ybf, Ss, Dd);
  k_gemm8<0, true><<<dim3(36, 1, Bb), b512, 0, stream>>>(
      ybf, ybf, nullptr, sc, nullptr, Dd, Dd, Dd, Ss, (long)Ss * Dd, (long)Ss * Dd,
      (long)Ss * Ss, scl);
  k_softmax<true><<<dim3(Bb * Ss), b256, 0, stream>>>(sc);
  k_gemm4<1, true><<<dim3(Dd / 256, Ss / 128, Bb), b512, 0, stream>>>(
      sc, T, attn, nullptr, nullptr, Ss, Ss, Ss, Dd,
      (long)Ss * Ss, (long)Dd * Ss, (long)Ss * Dd, 1.f);
  k_add_ln<<<dim3(Bb * Ss), b256, 0, stream>>>(y, attn, g1, be1, res, ybf);

  // --- cross-attention ---
  k_transpose_cast<<<dim3(Dd / 32, Ss / 32, Bb), dim3(32, 8), 0, stream>>>(Z, T, Zbf, Ss, Dd);
  k_gemm8<0, false><<<dim3(Ss / 256, Ss / 256, Bb), b512, 0, stream>>>(
      ybf, Zbf, nullptr, sc, nullptr, Dd, Dd, Dd, Ss, (long)Ss * Dd, (long)Ss * Dd,
      (long)Ss * Ss, scl);
  k_softmax<false><<<dim3(Bb * Ss), b256, 0, stream>>>(sc);
  k_gemm4<1, false><<<dim3(Dd / 256, Ss / 128, Bb), b512, 0, stream>>>(
      sc, T, attn, nullptr, nullptr, Ss, Ss, Ss, Dd,
      (long)Ss * Ss, (long)Dd * Ss, (long)Ss * Dd, 1.f);
  k_add_ln<<<dim3(Bb * Ss), b256, 0, stream>>>(res, attn, g2, be2, res, ybf);

  // --- FFN ---
  k_transpose_cast<<<dim3(Ff / 32, Dd / 32, 1), dim3(32, 8), 0, stream>>>(w1, w1t, nullptr, Dd, Ff);
  k_transpose_cast<<<dim3(Dd / 32, Ff / 32, 1), dim3(32, 8), 0, stream>>>(w2, w2t, nullptr, Ff, Dd);
  k_gemm8<2, false><<<dim3(Ff / 256, (Bb * Ss) / 256, 1), b512, 0, stream>>>(
      ybf, w1t, nullptr, h, b1, Dd, Dd, Dd, Ff, 0L, 0L, 0L, 1.f);
  k_gemm4<3, false><<<dim3(Dd / 256, (Bb * Ss) / 128, 1), b512, 0, stream>>>(
      h, w2t, attn, nullptr, b2, Ff, Ff, Ff, Dd, 0L, 0L, 0L, 1.f);
  k_add_ln<<<dim3(Bb * Ss), b256, 0, stream>>>(res, attn, g3, be3, out, nullptr);
}

// Round 5
// 396.731 us; speedup vs baseline: 1.3834x; 1.0169x over previous
//
#include <hip/hip_runtime.h>
#include <hip/hip_bf16.h>

// DecoderBlock: B=4, S=2048, D=1024, DFF=4096. fp32 in/out, bf16 MFMA internals.
// Round 5: balanced read distribution in k_gemm8 (gates at ph3/ph7 vmcnt(2),
// b0 pre-read at ph4/ph8 -> 8/8/4/4 reads/phase); residual fused into GEMM
// epilogues (EPI 4/5) + k_ln; causal softmax block-span trim.

#define Bb 4
#define Ss 2048
#define Dd 1024
#define Ff 4096

typedef __attribute__((ext_vector_type(4))) float f32x4;
typedef __attribute__((ext_vector_type(8))) short bf16x8;
typedef __attribute__((ext_vector_type(8))) unsigned short u16x8;
typedef __attribute__((ext_vector_type(4))) unsigned short u16x4;

__device__ __forceinline__ unsigned short f2bf(float f) {
  unsigned u = __float_as_uint(f);
  u += 0x7FFFu + ((u >> 16) & 1u);
  return (unsigned short)(u >> 16);
}
__device__ __forceinline__ float bf2f(unsigned short h) {
  return __uint_as_float(((unsigned)h) << 16);
}

__device__ __forceinline__ void gload_lds16(const void* g, void* l) {
  __builtin_amdgcn_global_load_lds((const __attribute__((address_space(1))) void*)g,
                                   (__attribute__((address_space(3))) void*)l, 16, 0, 0);
}

__device__ __forceinline__ int xcd8(int orig, int n) {
  int q = n >> 3, r = n & 7;
  int x = orig & 7;
  int base = x < r ? x * (q + 1) : r * (q + 1) + (x - r) * q;
  return base + (orig >> 3);
}

// ---------------- transpose+cast: in[R][C] fp32 -> outT[C][R] bf16 (+opt outR bf16) ----
__global__ __launch_bounds__(256) void k_transpose_cast(const float* __restrict__ in,
                                                        unsigned short* __restrict__ outT,
                                                        unsigned short* __restrict__ outR,
                                                        int R, int C) {
  __shared__ float t[32][33];
  size_t bo = (size_t)blockIdx.z * R * C;
  const float* pin = in + bo;
  unsigned short* poutT = outT + bo;
  unsigned short* poutR = outR ? outR + bo : nullptr;
  int c0 = blockIdx.x * 32, r0 = blockIdx.y * 32;
  int tx = threadIdx.x, ty = threadIdx.y;
#pragma unroll
  for (int i = 0; i < 4; i++) {
    float v = pin[(size_t)(r0 + ty + i * 8) * C + c0 + tx];
    t[ty + i * 8][tx] = v;
    if (poutR) poutR[(size_t)(r0 + ty + i * 8) * C + c0 + tx] = f2bf(v);
  }
  __syncthreads();
#pragma unroll
  for (int i = 0; i < 4; i++)
    poutT[(size_t)(c0 + ty + i * 8) * R + r0 + tx] = f2bf(t[tx][ty + i * 8]);
}

// ---- shared GEMM machinery --------------------------------------------------
// EPI: 0 *scale->bf16 | 2 bias+relu->bf16 | 4 v+resid->fp32 | 5 v+bias+resid->fp32
#define BAR() __builtin_amdgcn_s_barrier()
#define PRIO1() __builtin_amdgcn_s_setprio(1)
#define PRIO0() __builtin_amdgcn_s_setprio(0)
#define LGKM0()                                          \
  {                                                      \
    asm volatile("s_waitcnt lgkmcnt(0)" ::: "memory");   \
    __builtin_amdgcn_sched_barrier(0);                   \
  }

#define LDA8(arr, mh, bo)                                                       \
  {                                                                             \
    _Pragma("unroll") for (int j_ = 0; j_ < QM; ++j_) {                         \
      _Pragma("unroll") for (int kh_ = 0; kh_ < 2; ++kh_) {                     \
        arr[j_][kh_] =                                                          \
            *(const bf16x8*)(lds + (bo) + ((mh)*QM + j_) * 2048 + aof[kh_]);    \
      }                                                                         \
    }                                                                           \
  }

#define LDB8(arr, nh, bo)                                                       \
  {                                                                             \
    _Pragma("unroll") for (int n_ = 0; n_ < 2; ++n_) {                          \
      _Pragma("unroll") for (int kh_ = 0; kh_ < 2; ++kh_) {                     \
        arr[n_][kh_] =                                                          \
            *(const bf16x8*)(lds + (bo) + ((nh)*2 + n_) * 2048 + bof[kh_]);     \
      }                                                                         \
    }                                                                           \
  }

#define MMQ(aarr, barr, mh, nh)                                                 \
  {                                                                             \
    _Pragma("unroll") for (int j_ = 0; j_ < QM; ++j_) {                         \
      _Pragma("unroll") for (int n_ = 0; n_ < 2; ++n_) {                        \
        _Pragma("unroll") for (int kh_ = 0; kh_ < 2; ++kh_) {                   \
          acc[(mh)*QM + j_][(nh)*2 + n_] = __builtin_amdgcn_mfma_f32_16x16x32_bf16( \
              aarr[j_][kh_], barr[n_][kh_], acc[(mh)*QM + j_][(nh)*2 + n_], 0, 0, 0); \
        }                                                                       \
      }                                                                         \
    }                                                                           \
  }

#define EPILOGUE(MR_, WMS_)                                                     \
  {                                                                             \
    const int colb = j0 + wc * 64 + fr;                                         \
    const int rowb = i0 + wr * (WMS_) + (kq << 2);                              \
    const size_t cb = (size_t)bz * bsC;                                         \
    _Pragma("unroll") for (int m = 0; m < (MR_); ++m) {                         \
      _Pragma("unroll") for (int r = 0; r < 4; ++r) {                           \
        size_t ro = cb + (size_t)(rowb + m * 16 + r) * ldc;                     \
        _Pragma("unroll") for (int n = 0; n < 4; ++n) {                         \
          float v = acc[m][n][r];                                               \
          int col = colb + n * 16;                                              \
          if (EPI == 0) Cb[ro + col] = f2bf(v * scale);                         \
          else if (EPI == 2) Cb[ro + col] = f2bf(fmaxf(v + bias[col], 0.f));    \
          else if (EPI == 4) Cf[ro + col] = v + resid[ro + col];                \
          else Cf[ro + col] = v + bias[col] + resid[ro + col];                  \
        }                                                                       \
      }                                                                         \
    }                                                                           \
  }

// ========================= k_gemm8: BMt=256, 8-phase, balanced reads =========
template <int EPI, bool CAUSAL>
__global__ __launch_bounds__(512) void k_gemm8(
    const unsigned short* __restrict__ Ag, const unsigned short* __restrict__ Bg,
    float* __restrict__ Cf, unsigned short* __restrict__ Cb,
    const float* __restrict__ bias, const float* __restrict__ resid,
    int K, int lda, int ldb, int ldc, long bsA, long bsB, long bsC, float scale) {
  constexpr int QM = 4;
  constexpr int ABYTES = 32768, BBYTES = 32768;
  __shared__ alignas(16) char lds[2 * ABYTES + 2 * BBYTES];

  int i0, j0;
  if (CAUSAL) {
    int t = xcd8(blockIdx.x, gridDim.x);
    int ti = (int)((sqrtf(8.f * t + 1.f) - 1.f) * 0.5f);
    while ((ti + 1) * (ti + 2) / 2 <= t) ++ti;
    while (ti * (ti + 1) / 2 > t) --ti;
    i0 = ti * 256;
    j0 = (t - ti * (ti + 1) / 2) * 256;
  } else {
    int lin = xcd8(blockIdx.y * gridDim.x + blockIdx.x, gridDim.x * gridDim.y);
    i0 = (lin / gridDim.x) * 256;
    j0 = (lin % gridDim.x) * 256;
  }
  int bz = blockIdx.z;
  Ag += (size_t)bz * bsA;
  Bg += (size_t)bz * bsB;

  const int nk = K / 64;
  const int niter = nk / 2;

  const int tid = threadIdx.x;
  const int w = tid >> 6, lane = tid & 63;
  const int wr = w >> 2, wc = w & 3;

  const int srow = (w << 3) + (lane >> 3);
  const int bcs = (lane & 7) ^ (lane >> 3);
  const unsigned short* As = Ag + (size_t)(i0 + srow) * lda + bcs * 8;
  const unsigned short* Bs = Bg + (size_t)(j0 + srow) * ldb + bcs * 8;
  char* ldsAw = lds + w * 1024;
  char* ldsBw = lds + 2 * ABYTES + w * 1024;

  auto stA = [&](int kt, int hf) {
    int ks = kt < nk ? kt : nk - 1;
#pragma unroll
    for (int l = 0; l < 2; ++l)
      gload_lds16(As + (size_t)(hf * 128 + l * 64) * lda + ks * 64,
                  ldsAw + (kt & 1) * ABYTES + hf * 128 * 128 + l * 8192);
  };
  auto stB = [&](int kt, int hf) {
    int ks = kt < nk ? kt : nk - 1;
#pragma unroll
    for (int l = 0; l < 2; ++l)
      gload_lds16(Bs + (size_t)(hf * 128 + l * 64) * ldb + ks * 64,
                  ldsBw + (kt & 1) * BBYTES + hf * 128 * 128 + l * 8192);
  };

  const int fr = lane & 15, kq = lane >> 4;
  const int rA = wr * 128 + fr;
  const int rB = wc * 64 + fr;
  unsigned aof[2], bof[2];
  aof[0] = rA * 128 + ((kq ^ (rA & 7)) << 4);
  aof[1] = rA * 128 + (((kq + 4) ^ (rA & 7)) << 4);
  bof[0] = 2 * ABYTES + rB * 128 + ((kq ^ (rB & 7)) << 4);
  bof[1] = 2 * ABYTES + rB * 128 + (((kq + 4) ^ (rB & 7)) << 4);
  constexpr int A0 = 0, A1 = ABYTES, B0 = 0, B1 = BBYTES;

  f32x4 acc[8][4];
#pragma unroll
  for (int m = 0; m < 8; ++m)
#pragma unroll
    for (int n = 0; n < 4; ++n) acc[m][n] = (f32x4){0.f, 0.f, 0.f, 0.f};

  bf16x8 a0[QM][2], a1[QM][2], b0[2][2], b1[2][2];

  // prologue: 7 half-tiles; drain tile0 (vmcnt(6)); barrier; pre-read b0(buf0)
  stA(0, 0); stA(0, 1); stB(0, 0); stB(0, 1);
  stA(1, 0); stA(1, 1); stB(1, 0);
  asm volatile("s_waitcnt vmcnt(6)" ::: "memory");
  BAR();
  LDB8(b0, 0, B0);

  // steady state per-wave vmcnt audit: post-prologue 6 outstanding;
  // ph1 +2 -> 8; ph3 +2 -> 10, vmcnt(2) drains 8 = tile(2t+1) complete;
  // ph4 +4 -> 6; ph5 +2 -> 8; ph7 +2 -> 10, vmcnt(2) drains 8 = tile(ka).
  for (int t = 0; t < niter; ++t) {
    const int ka = 2 * t + 2, kb = 2 * t + 3;
    // ph1: reads a0(buf0, 8); stage B(2t+1)h1 (last read prev ph7)
    LDA8(a0, 0, A0);
    stB(2 * t + 1, 1);
    BAR(); LGKM0(); PRIO1(); MMQ(a0, b0, 0, 0); PRIO0(); BAR();
    // ph2: a1 (8)
    LDA8(a1, 1, A0);
    BAR(); LGKM0(); PRIO1(); MMQ(a1, b0, 1, 0); PRIO0(); BAR();
    // ph3: b1 (4); stage A(ka)h0 (buf0-A last read ph2); GATE tile(2t+1)
    LDB8(b1, 1, B0);
    stA(ka, 0);
    asm volatile("s_waitcnt vmcnt(2)" ::: "memory");
    BAR(); LGKM0(); PRIO1(); MMQ(a1, b1, 1, 1); PRIO0(); BAR();
    // ph4: pre-read b0(buf1, visible post-ph3-barrier); stage A(ka)h1,B(ka)h0
    LDB8(b0, 0, B1);
    stA(ka, 1); stB(ka, 0);
    BAR(); LGKM0(); PRIO1(); MMQ(a0, b1, 0, 1); PRIO0(); BAR();
    // ph5: a0(buf1, 8); stage B(ka)h1 (buf0-B last read ph3)
    LDA8(a0, 0, A1);
    stB(ka, 1);
    BAR(); LGKM0(); PRIO1(); MMQ(a0, b0, 0, 0); PRIO0(); BAR();
    // ph6: a1 (8)
    LDA8(a1, 1, A1);
    BAR(); LGKM0(); PRIO1(); MMQ(a1, b0, 1, 0); PRIO0(); BAR();
    // ph7: b1 (4); stage A(kb)h0 (buf1-A last read ph6); GATE tile(ka)
    LDB8(b1, 1, B1);
    stA(kb, 0);
    asm volatile("s_waitcnt vmcnt(2)" ::: "memory");
    BAR(); LGKM0(); PRIO1(); MMQ(a1, b1, 1, 1); PRIO0(); BAR();
    // ph8: pre-read b0(buf0 next, visible post-ph7-barrier); stage A(kb)h1,B(kb)h0
    LDB8(b0, 0, B0);
    stA(kb, 1); stB(kb, 0);
    BAR(); LGKM0(); PRIO1(); MMQ(a0, b1, 0, 1); PRIO0(); BAR();
  }
  EPILOGUE(8, 128)
}

// ========================= k_gemm4: BMt=128, 4-phase =========================
template <int EPI, bool KCAP>
__global__ __launch_bounds__(512) void k_gemm4(
    const unsigned short* __restrict__ Ag, const unsigned short* __restrict__ Bg,
    float* __restrict__ Cf, unsigned short* __restrict__ Cb,
    const float* __restrict__ bias, const float* __restrict__ resid,
    int K, int lda, int ldb, int ldc, long bsA, long bsB, long bsC, float scale) {
  constexpr int QM = 4;
  constexpr int ABYTES = 16384, BBYTES = 32768;
  __shared__ alignas(16) char lds[2 * ABYTES + 2 * BBYTES];

  int lin = xcd8(blockIdx.y * gridDim.x + blockIdx.x, gridDim.x * gridDim.y);
  int i0 = (lin / gridDim.x) * 128;
  int j0 = (lin % gridDim.x) * 256;
  int bz = blockIdx.z;
  Ag += (size_t)bz * bsA;
  Bg += (size_t)bz * bsB;

  int nk = K / 64;
  if (KCAP) {
    int cap = i0 / 64 + 2;
    nk = nk < cap ? nk : cap;
  }
  const int niter = nk / 2;

  const int tid = threadIdx.x;
  const int w = tid >> 6, lane = tid & 63;
  const int wr = w >> 2, wc = w & 3;

  const int srow = (w << 3) + (lane >> 3);
  const int bcs = (lane & 7) ^ (lane >> 3);
  const unsigned short* As = Ag + (size_t)(i0 + srow) * lda + bcs * 8;
  const unsigned short* Bs = Bg + (size_t)(j0 + srow) * ldb + bcs * 8;
  char* ldsAw = lds + w * 1024;
  char* ldsBw = lds + 2 * ABYTES + w * 1024;

  auto stA2 = [&](int kt) {
    int ks = kt < nk ? kt : nk - 1;
#pragma unroll
    for (int hf = 0; hf < 2; ++hf)
      gload_lds16(As + (size_t)(hf * 64) * lda + ks * 64,
                  ldsAw + (kt & 1) * ABYTES + hf * 64 * 128);
  };
  auto stB2 = [&](int kt) {
    int ks = kt < nk ? kt : nk - 1;
#pragma unroll
    for (int hf = 0; hf < 2; ++hf)
#pragma unroll
      for (int l = 0; l < 2; ++l)
        gload_lds16(Bs + (size_t)(hf * 128 + l * 64) * ldb + ks * 64,
                    ldsBw + (kt & 1) * BBYTES + hf * 128 * 128 + l * 8192);
  };

  const int fr = lane & 15, kq = lane >> 4;
  const int rA = wr * 64 + fr;
  const int rB = wc * 64 + fr;
  unsigned aof[2], bof[2];
  aof[0] = rA * 128 + ((kq ^ (rA & 7)) << 4);
  aof[1] = rA * 128 + (((kq + 4) ^ (rA & 7)) << 4);
  bof[0] = 2 * ABYTES + rB * 128 + ((kq ^ (rB & 7)) << 4);
  bof[1] = 2 * ABYTES + rB * 128 + (((kq + 4) ^ (rB & 7)) << 4);
  constexpr int A0 = 0, A1 = ABYTES, B0 = 0, B1 = BBYTES;

  f32x4 acc[4][4];
#pragma unroll
  for (int m = 0; m < 4; ++m)
#pragma unroll
    for (int n = 0; n < 4; ++n) acc[m][n] = (f32x4){0.f, 0.f, 0.f, 0.f};

  bf16x8 a[QM][2], b0[2][2], b1[2][2];

  stA2(0); stB2(0); stA2(1);
  asm volatile("s_waitcnt vmcnt(2)" ::: "memory");
  BAR();

  for (int t = 0; t < niter; ++t) {
    const int ka = 2 * t + 2, kb = 2 * t + 3;
    LDA8(a, 0, A0); LDB8(b0, 0, B0);
    stB2(2 * t + 1);
    BAR(); LGKM0(); PRIO1(); MMQ(a, b0, 0, 0); PRIO0(); BAR();
    LDB8(b1, 1, B0);
    stA2(ka);
    asm volatile("s_waitcnt vmcnt(2)" ::: "memory");
    BAR(); LGKM0(); PRIO1(); MMQ(a, b1, 0, 1); PRIO0(); BAR();
    LDA8(a, 0, A1); LDB8(b0, 0, B1);
    stB2(ka);
    BAR(); LGKM0(); PRIO1(); MMQ(a, b0, 0, 0); PRIO0(); BAR();
    LDB8(b1, 1, B1);
    stA2(kb);
    asm volatile("s_waitcnt vmcnt(2)" ::: "memory");
    BAR(); LGKM0(); PRIO1(); MMQ(a, b1, 0, 1); PRIO0(); BAR();
  }
  EPILOGUE(4, 64)
}

// ---------------- row softmax, bf16 scores -> bf16 P in place ----------------
// CAUSAL: only the 128-aligned block span [0, (i&~127)+128) is touched; the
// zero-fill through that span exactly covers PV1's KCAP read range.
template <bool CAUSAL>
__global__ __launch_bounds__(256) void k_softmax(unsigned short* __restrict__ scores) {
  int row = blockIdx.x;  // b*S + i
  int i = row & (Ss - 1);
  unsigned short* src = scores + (size_t)row * Ss;
  int nv = CAUSAL ? i + 1 : Ss;
  int nb = CAUSAL ? ((i & ~127) + 128) : Ss;
  int t = threadIdx.x;
  int w = t >> 6, lane = t & 63;
  bool act = t * 8 < nb;
  float v[8];
  float mx = -1e30f;
  if (act) {
    u16x8 raw = *(const u16x8*)(src + t * 8);
#pragma unroll
    for (int k = 0; k < 8; k++) {
      int j = t * 8 + k;
      v[k] = (j < nv) ? bf2f(raw[k]) : -1e30f;
      mx = fmaxf(mx, v[k]);
    }
  } else {
#pragma unroll
    for (int k = 0; k < 8; k++) v[k] = -1e30f;
  }
#pragma unroll
  for (int o = 32; o; o >>= 1) mx = fmaxf(mx, __shfl_xor(mx, o));
  __shared__ float red[8];
  if (lane == 0) red[w] = mx;
  __syncthreads();
  mx = fmaxf(fmaxf(red[0], red[1]), fmaxf(red[2], red[3]));
  float sum = 0.f;
#pragma unroll
  for (int k = 0; k < 8; k++) {
    float e = (v[k] > -1e29f) ? __expf(v[k] - mx) : 0.f;
    v[k] = e;
    sum += e;
  }
#pragma unroll
  for (int o = 32; o; o >>= 1) sum += __shfl_xor(sum, o);
  if (lane == 0) red[4 + w] = sum;
  __syncthreads();
  sum = red[4] + red[5] + red[6] + red[7];
  float inv = 1.f / sum;
  if (act) {
    u16x8 r;
#pragma unroll
    for (int k = 0; k < 8; k++) r[k] = f2bf(v[k] * inv);
    *(u16x8*)(src + t * 8) = r;
  }
}

// ---------------- LayerNorm (input already has residual added) ----------------
__global__ __launch_bounds__(256) void k_ln(const float* __restrict__ a,
                                            const float* __restrict__ g,
                                            const float* __restrict__ be,
                                            float* __restrict__ outf,
                                            unsigned short* __restrict__ outb) {
  int row = blockIdx.x;
  size_t o = (size_t)row * Dd;
  int t = threadIdx.x;
  f32x4 x = *(const f32x4*)(a + o + t * 4);
  float s = x[0] + x[1] + x[2] + x[3];
  float q = x[0] * x[0] + x[1] * x[1] + x[2] * x[2] + x[3] * x[3];
  int w = t >> 6, lane = t & 63;
#pragma unroll
  for (int of = 32; of; of >>= 1) {
    s += __shfl_xor(s, of);
    q += __shfl_xor(q, of);
  }
  __shared__ float red[8];
  if (lane == 0) {
    red[w] = s;
    red[4 + w] = q;
  }
  __syncthreads();
  s = red[0] + red[1] + red[2] + red[3];
  q = red[4] + red[5] + red[6] + red[7];
  float mean = s * (1.f / Dd);
  float var = q * (1.f / Dd) - mean * mean;
  float rstd = rsqrtf(var + 1e-5f);
  f32x4 gv = *(const f32x4*)(g + t * 4);
  f32x4 bv = *(const f32x4*)(be + t * 4);
  f32x4 y;
#pragma unroll
  for (int k = 0; k < 4; k++) y[k] = (x[k] - mean) * rstd * gv[k] + bv[k];
  *(f32x4*)(outf + o + t * 4) = y;
  if (outb) {
    u16x4 r;
    r[0] = f2bf(y[0]); r[1] = f2bf(y[1]); r[2] = f2bf(y[2]); r[3] = f2bf(y[3]);
    *(u16x4*)(outb + o + t * 4) = r;
  }
}

extern "C" void kernel_launch(void* const* d_in, const int* in_sizes, int n_in, void* d_out,
                              int out_size, void* d_ws, size_t ws_size, hipStream_t stream) {
  (void)in_sizes; (void)n_in; (void)out_size; (void)ws_size;
  const float* y   = (const float*)d_in[0];
  const float* Z   = (const float*)d_in[1];
  const float* w1  = (const float*)d_in[2];
  const float* b1  = (const float*)d_in[3];
  const float* w2  = (const float*)d_in[4];
  const float* b2  = (const float*)d_in[5];
  const float* g1  = (const float*)d_in[6];
  const float* be1 = (const float*)d_in[7];
  const float* g2  = (const float*)d_in[8];
  const float* be2 = (const float*)d_in[9];
  const float* g3  = (const float*)d_in[10];
  const float* be3 = (const float*)d_in[11];
  float* out = (float*)d_out;

  char* ws = (char*)d_ws;
  const size_t MB = 1024ull * 1024ull;
  unsigned short* T   = (unsigned short*)(ws);            // y^T then Z^T (bf16)
  unsigned short* Zbf = (unsigned short*)(ws + 16 * MB);  // Z bf16
  unsigned short* ybf = (unsigned short*)(ws + 32 * MB);  // y / y1 / y2 bf16
  unsigned short* w1t = (unsigned short*)(ws + 48 * MB);  // w1^T bf16
  unsigned short* w2t = (unsigned short*)(ws + 56 * MB);  // w2^T bf16
  unsigned short* sc  = (unsigned short*)(ws + 64 * MB);  // scores/P bf16 (32MB)
  unsigned short* h   = (unsigned short*)(ws + 64 * MB);  // h bf16 (64MB) aliases dead sc
  float* res          = (float*)(ws + 128 * MB);          // residual stream fp32
  float* attn         = (float*)d_out;                    // attn / ff scratch

  dim3 b256(256), b512(512);
  const float scl = 1.f / 32.f;

  // --- self-attention ---
  k_transpose_cast<<<dim3(Dd / 32, Ss / 32, Bb), dim3(32, 8), 0, stream>>>(y, T, ybf, Ss, Dd);
  k_gemm8<0, true><<<dim3(36, 1, Bb), b512, 0, stream>>>(
      ybf, ybf, nullptr, sc, nullptr, nullptr, Dd, Dd, Dd, Ss,
      (long)Ss * Dd, (long)Ss * Dd, (long)Ss * Ss, scl);
  k_softmax<true><<<dim3(Bb * Ss), b256, 0, stream>>>(sc);
  k_gemm4<4, true><<<dim3(Dd / 256, Ss / 128, Bb), b512, 0, stream>>>(
      sc, T, attn, nullptr, nullptr, y, Ss, Ss, Ss, Dd,
      (long)Ss * Ss, (long)Dd * Ss, (long)Ss * Dd, 1.f);
  k_ln<<<dim3(Bb * Ss), b256, 0, stream>>>(attn, g1, be1, res, ybf);

  // --- cross-attention ---
  k_transpose_cast<<<dim3(Dd / 32, Ss / 32, Bb), dim3(32, 8), 0, stream>>>(Z, T, Zbf, Ss, Dd);
  k_gemm8<0, false><<<dim3(Ss / 256, Ss / 256, Bb), b512, 0, stream>>>(
      ybf, Zbf, nullptr, sc, nullptr, nullptr, Dd, Dd, Dd, Ss,
      (long)Ss * Dd, (long)Ss * Dd, (long)Ss * Ss, scl);
  k_softmax<false><<<dim3(Bb * Ss), b256, 0, stream>>>(sc);
  k_gemm4<4, false><<<dim3(Dd / 256, Ss / 128, Bb), b512, 0, stream>>>(
      sc, T, attn, nullptr, nullptr, res, Ss, Ss, Ss, Dd,
      (long)Ss * Ss, (long)Dd * Ss, (long)Ss * Dd, 1.f);
  k_ln<<<dim3(Bb * Ss), b256, 0, stream>>>(attn, g2, be2, res, ybf);

  // --- FFN ---
  k_transpose_cast<<<dim3(Ff / 32, Dd / 32, 1), dim3(32, 8), 0, stream>>>(w1, w1t, nullptr, Dd, Ff);
  k_transpose_cast<<<dim3(Dd / 32, Ff / 32, 1), dim3(32, 8), 0, stream>>>(w2, w2t, nullptr, Ff, Dd);
  k_gemm8<2, false><<<dim3(Ff / 256, (Bb * Ss) / 256, 1), b512, 0, stream>>>(
      ybf, w1t, nullptr, h, b1, nullptr, Dd, Dd, Dd, Ff, 0L, 0L, 0L, 1.f);
  k_gemm4<5, false><<<dim3(Dd / 256, (Bb * Ss) / 128, 1), b512, 0, stream>>>(
      h, w2t, attn, nullptr, b2, res, Ff, Ff, Ff, Dd, 0L, 0L, 0L, 1.f);
  k_ln<<<dim3(Bb * Ss), b256, 0, stream>>>(attn, g3, be3, out, nullptr);
}

// Round 6
// 393.648 us; speedup vs baseline: 1.3942x; 1.0078x over previous
//
#include <hip/hip_runtime.h>
#include <hip/hip_bf16.h>

// DecoderBlock: B=4, S=2048, D=1024, DFF=4096. fp32 in/out, bf16 MFMA internals.
// Round 6: exact m201-template stage/gate geometry — 1 half-tile staged per
// phase (placed immediately after that half's last ds_read; half-granularity
// WAR is safe with >=1 barrier separation), gates ONLY at ph4/ph8 vmcnt(6)
// (k_gemm8) / ph2/ph4 vmcnt(4) (k_gemm4), giving every gated load a 3-phase
// latency margin. Only the GEMM schedule changed vs R5.

#define Bb 4
#define Ss 2048
#define Dd 1024
#define Ff 4096

typedef __attribute__((ext_vector_type(4))) float f32x4;
typedef __attribute__((ext_vector_type(8))) short bf16x8;
typedef __attribute__((ext_vector_type(8))) unsigned short u16x8;
typedef __attribute__((ext_vector_type(4))) unsigned short u16x4;

__device__ __forceinline__ unsigned short f2bf(float f) {
  unsigned u = __float_as_uint(f);
  u += 0x7FFFu + ((u >> 16) & 1u);
  return (unsigned short)(u >> 16);
}
__device__ __forceinline__ float bf2f(unsigned short h) {
  return __uint_as_float(((unsigned)h) << 16);
}

__device__ __forceinline__ void gload_lds16(const void* g, void* l) {
  __builtin_amdgcn_global_load_lds((const __attribute__((address_space(1))) void*)g,
                                   (__attribute__((address_space(3))) void*)l, 16, 0, 0);
}

__device__ __forceinline__ int xcd8(int orig, int n) {
  int q = n >> 3, r = n & 7;
  int x = orig & 7;
  int base = x < r ? x * (q + 1) : r * (q + 1) + (x - r) * q;
  return base + (orig >> 3);
}

// ---------------- transpose+cast: in[R][C] fp32 -> outT[C][R] bf16 (+opt outR bf16) ----
__global__ __launch_bounds__(256) void k_transpose_cast(const float* __restrict__ in,
                                                        unsigned short* __restrict__ outT,
                                                        unsigned short* __restrict__ outR,
                                                        int R, int C) {
  __shared__ float t[32][33];
  size_t bo = (size_t)blockIdx.z * R * C;
  const float* pin = in + bo;
  unsigned short* poutT = outT + bo;
  unsigned short* poutR = outR ? outR + bo : nullptr;
  int c0 = blockIdx.x * 32, r0 = blockIdx.y * 32;
  int tx = threadIdx.x, ty = threadIdx.y;
#pragma unroll
  for (int i = 0; i < 4; i++) {
    float v = pin[(size_t)(r0 + ty + i * 8) * C + c0 + tx];
    t[ty + i * 8][tx] = v;
    if (poutR) poutR[(size_t)(r0 + ty + i * 8) * C + c0 + tx] = f2bf(v);
  }
  __syncthreads();
#pragma unroll
  for (int i = 0; i < 4; i++)
    poutT[(size_t)(c0 + ty + i * 8) * R + r0 + tx] = f2bf(t[tx][ty + i * 8]);
}

// ---- shared GEMM machinery --------------------------------------------------
// EPI: 0 *scale->bf16 | 2 bias+relu->bf16 | 4 v+resid->fp32 | 5 v+bias+resid->fp32
#define BAR() __builtin_amdgcn_s_barrier()
#define PRIO1() __builtin_amdgcn_s_setprio(1)
#define PRIO0() __builtin_amdgcn_s_setprio(0)
#define LGKM0()                                          \
  {                                                      \
    asm volatile("s_waitcnt lgkmcnt(0)" ::: "memory");   \
    __builtin_amdgcn_sched_barrier(0);                   \
  }

#define LDA8(arr, mh, bo)                                                       \
  {                                                                             \
    _Pragma("unroll") for (int j_ = 0; j_ < QM; ++j_) {                         \
      _Pragma("unroll") for (int kh_ = 0; kh_ < 2; ++kh_) {                     \
        arr[j_][kh_] =                                                          \
            *(const bf16x8*)(lds + (bo) + ((mh)*QM + j_) * 2048 + aof[kh_]);    \
      }                                                                         \
    }                                                                           \
  }

#define LDB8(arr, nh, bo)                                                       \
  {                                                                             \
    _Pragma("unroll") for (int n_ = 0; n_ < 2; ++n_) {                          \
      _Pragma("unroll") for (int kh_ = 0; kh_ < 2; ++kh_) {                     \
        arr[n_][kh_] =                                                          \
            *(const bf16x8*)(lds + (bo) + ((nh)*2 + n_) * 2048 + bof[kh_]);     \
      }                                                                         \
    }                                                                           \
  }

#define MMQ(aarr, barr, mh, nh)                                                 \
  {                                                                             \
    _Pragma("unroll") for (int j_ = 0; j_ < QM; ++j_) {                         \
      _Pragma("unroll") for (int n_ = 0; n_ < 2; ++n_) {                        \
        _Pragma("unroll") for (int kh_ = 0; kh_ < 2; ++kh_) {                   \
          acc[(mh)*QM + j_][(nh)*2 + n_] = __builtin_amdgcn_mfma_f32_16x16x32_bf16( \
              aarr[j_][kh_], barr[n_][kh_], acc[(mh)*QM + j_][(nh)*2 + n_], 0, 0, 0); \
        }                                                                       \
      }                                                                         \
    }                                                                           \
  }

#define EPILOGUE(MR_, WMS_)                                                     \
  {                                                                             \
    const int colb = j0 + wc * 64 + fr;                                         \
    const int rowb = i0 + wr * (WMS_) + (kq << 2);                              \
    const size_t cb = (size_t)bz * bsC;                                         \
    _Pragma("unroll") for (int m = 0; m < (MR_); ++m) {                         \
      _Pragma("unroll") for (int r = 0; r < 4; ++r) {                           \
        size_t ro = cb + (size_t)(rowb + m * 16 + r) * ldc;                     \
        _Pragma("unroll") for (int n = 0; n < 4; ++n) {                         \
          float v = acc[m][n][r];                                               \
          int col = colb + n * 16;                                              \
          if (EPI == 0) Cb[ro + col] = f2bf(v * scale);                         \
          else if (EPI == 2) Cb[ro + col] = f2bf(fmaxf(v + bias[col], 0.f));    \
          else if (EPI == 4) Cf[ro + col] = v + resid[ro + col];                \
          else Cf[ro + col] = v + bias[col] + resid[ro + col];                  \
        }                                                                       \
      }                                                                         \
    }                                                                           \
  }

// ========================= k_gemm8: BMt=256, 8-phase, template geometry ======
template <int EPI, bool CAUSAL>
__global__ __launch_bounds__(512) void k_gemm8(
    const unsigned short* __restrict__ Ag, const unsigned short* __restrict__ Bg,
    float* __restrict__ Cf, unsigned short* __restrict__ Cb,
    const float* __restrict__ bias, const float* __restrict__ resid,
    int K, int lda, int ldb, int ldc, long bsA, long bsB, long bsC, float scale) {
  constexpr int QM = 4;
  constexpr int ABYTES = 32768, BBYTES = 32768;
  __shared__ alignas(16) char lds[2 * ABYTES + 2 * BBYTES];

  int i0, j0;
  if (CAUSAL) {
    int t = xcd8(blockIdx.x, gridDim.x);
    int ti = (int)((sqrtf(8.f * t + 1.f) - 1.f) * 0.5f);
    while ((ti + 1) * (ti + 2) / 2 <= t) ++ti;
    while (ti * (ti + 1) / 2 > t) --ti;
    i0 = ti * 256;
    j0 = (t - ti * (ti + 1) / 2) * 256;
  } else {
    int lin = xcd8(blockIdx.y * gridDim.x + blockIdx.x, gridDim.x * gridDim.y);
    i0 = (lin / gridDim.x) * 256;
    j0 = (lin % gridDim.x) * 256;
  }
  int bz = blockIdx.z;
  Ag += (size_t)bz * bsA;
  Bg += (size_t)bz * bsB;

  const int nk = K / 64;
  const int niter = nk / 2;

  const int tid = threadIdx.x;
  const int w = tid >> 6, lane = tid & 63;
  const int wr = w >> 2, wc = w & 3;

  const int srow = (w << 3) + (lane >> 3);
  const int bcs = (lane & 7) ^ (lane >> 3);
  const unsigned short* As = Ag + (size_t)(i0 + srow) * lda + bcs * 8;
  const unsigned short* Bs = Bg + (size_t)(j0 + srow) * ldb + bcs * 8;
  char* ldsAw = lds + w * 1024;
  char* ldsBw = lds + 2 * ABYTES + w * 1024;

  auto stA = [&](int kt, int hf) {
    int ks = kt < nk ? kt : nk - 1;
#pragma unroll
    for (int l = 0; l < 2; ++l)
      gload_lds16(As + (size_t)(hf * 128 + l * 64) * lda + ks * 64,
                  ldsAw + (kt & 1) * ABYTES + hf * 128 * 128 + l * 8192);
  };
  auto stB = [&](int kt, int hf) {
    int ks = kt < nk ? kt : nk - 1;
#pragma unroll
    for (int l = 0; l < 2; ++l)
      gload_lds16(Bs + (size_t)(hf * 128 + l * 64) * ldb + ks * 64,
                  ldsBw + (kt & 1) * BBYTES + hf * 128 * 128 + l * 8192);
  };

  const int fr = lane & 15, kq = lane >> 4;
  const int rA = wr * 128 + fr;
  const int rB = wc * 64 + fr;
  unsigned aof[2], bof[2];
  aof[0] = rA * 128 + ((kq ^ (rA & 7)) << 4);
  aof[1] = rA * 128 + (((kq + 4) ^ (rA & 7)) << 4);
  bof[0] = 2 * ABYTES + rB * 128 + ((kq ^ (rB & 7)) << 4);
  bof[1] = 2 * ABYTES + rB * 128 + (((kq + 4) ^ (rB & 7)) << 4);
  constexpr int A0 = 0, A1 = ABYTES, B0 = 0, B1 = BBYTES;

  f32x4 acc[8][4];
#pragma unroll
  for (int m = 0; m < 8; ++m)
#pragma unroll
    for (int n = 0; n < 4; ++n) acc[m][n] = (f32x4){0.f, 0.f, 0.f, 0.f};

  bf16x8 a0[QM][2], a1[QM][2], b0[2][2], b1[2][2];

  // prologue: 7 half-tiles; vmcnt(6) drains tile0's 8 loads (tile1's 6 in flight)
  stA(0, 0); stA(0, 1); stB(0, 0); stB(0, 1);
  stA(1, 0); stA(1, 1); stB(1, 0);
  asm volatile("s_waitcnt vmcnt(6)" ::: "memory");
  BAR();

  // WAR audit (slot <- stage phase, slot's last ds_read phase):
  //  buf1-Bh1 <- ph1 (read prev ph7) | buf0-Ah0 <- ph2 (ph1) | buf0-Ah1 <- ph3 (ph2)
  //  buf0-Bh0 <- ph4 (ph1) | buf0-Bh1 <- ph5 (ph3) | buf1-Ah0 <- ph6 (ph5)
  //  buf1-Ah1 <- ph7 (ph6) | buf1-Bh0 <- ph8 (ph5)   — all >=1 barrier apart.
  // Gate audit: ph4 vmcnt(6) keeps [A(ka)h0,A(ka)h1,B(ka)h0] -> tile(2t+1)
  //  fully landed before ph5 reads buf1; ph8 vmcnt(6) keeps [A(kb)h0,h1,B(kb)h0]
  //  -> tile(ka) landed before next ph1 reads buf0. 3-phase latency margin.
  for (int t = 0; t < niter; ++t) {
    const int ka = 2 * t + 2, kb = 2 * t + 3;
    // ph1: 12 reads (a0+b0, buf0); stage B(2t+1)h1
    LDA8(a0, 0, A0); LDB8(b0, 0, B0);
    stB(2 * t + 1, 1);
    BAR(); LGKM0(); PRIO1(); MMQ(a0, b0, 0, 0); PRIO0(); BAR();
    // ph2: 8 reads (a1); stage A(ka)h0
    LDA8(a1, 1, A0);
    stA(ka, 0);
    BAR(); LGKM0(); PRIO1(); MMQ(a1, b0, 1, 0); PRIO0(); BAR();
    // ph3: 4 reads (b1); stage A(ka)h1
    LDB8(b1, 1, B0);
    stA(ka, 1);
    BAR(); LGKM0(); PRIO1(); MMQ(a1, b1, 1, 1); PRIO0(); BAR();
    // ph4: 0 reads; stage B(ka)h0; GATE
    stB(ka, 0);
    asm volatile("s_waitcnt vmcnt(6)" ::: "memory");
    BAR(); PRIO1(); MMQ(a0, b1, 0, 1); PRIO0(); BAR();
    // ph5: 12 reads (a0+b0, buf1); stage B(ka)h1
    LDA8(a0, 0, A1); LDB8(b0, 0, B1);
    stB(ka, 1);
    BAR(); LGKM0(); PRIO1(); MMQ(a0, b0, 0, 0); PRIO0(); BAR();
    // ph6: 8 reads (a1); stage A(kb)h0
    LDA8(a1, 1, A1);
    stA(kb, 0);
    BAR(); LGKM0(); PRIO1(); MMQ(a1, b0, 1, 0); PRIO0(); BAR();
    // ph7: 4 reads (b1); stage A(kb)h1
    LDB8(b1, 1, B1);
    stA(kb, 1);
    BAR(); LGKM0(); PRIO1(); MMQ(a1, b1, 1, 1); PRIO0(); BAR();
    // ph8: 0 reads; stage B(kb)h0; GATE
    stB(kb, 0);
    asm volatile("s_waitcnt vmcnt(6)" ::: "memory");
    BAR(); PRIO1(); MMQ(a0, b1, 0, 1); PRIO0(); BAR();
  }
  EPILOGUE(8, 128)
}

// ========================= k_gemm4: BMt=128, 4-phase, template geometry ======
template <int EPI, bool KCAP>
__global__ __launch_bounds__(512) void k_gemm4(
    const unsigned short* __restrict__ Ag, const unsigned short* __restrict__ Bg,
    float* __restrict__ Cf, unsigned short* __restrict__ Cb,
    const float* __restrict__ bias, const float* __restrict__ resid,
    int K, int lda, int ldb, int ldc, long bsA, long bsB, long bsC, float scale) {
  constexpr int QM = 4;
  constexpr int ABYTES = 16384, BBYTES = 32768;
  __shared__ alignas(16) char lds[2 * ABYTES + 2 * BBYTES];

  int lin = xcd8(blockIdx.y * gridDim.x + blockIdx.x, gridDim.x * gridDim.y);
  int i0 = (lin / gridDim.x) * 128;
  int j0 = (lin % gridDim.x) * 256;
  int bz = blockIdx.z;
  Ag += (size_t)bz * bsA;
  Bg += (size_t)bz * bsB;

  int nk = K / 64;
  if (KCAP) {
    int cap = i0 / 64 + 2;
    nk = nk < cap ? nk : cap;
  }
  const int niter = nk / 2;

  const int tid = threadIdx.x;
  const int w = tid >> 6, lane = tid & 63;
  const int wr = w >> 2, wc = w & 3;

  const int srow = (w << 3) + (lane >> 3);
  const int bcs = (lane & 7) ^ (lane >> 3);
  const unsigned short* As = Ag + (size_t)(i0 + srow) * lda + bcs * 8;
  const unsigned short* Bs = Bg + (size_t)(j0 + srow) * ldb + bcs * 8;
  char* ldsAw = lds + w * 1024;
  char* ldsBw = lds + 2 * ABYTES + w * 1024;

  auto stA2 = [&](int kt) {  // full A tile (2 instr)
    int ks = kt < nk ? kt : nk - 1;
#pragma unroll
    for (int hf = 0; hf < 2; ++hf)
      gload_lds16(As + (size_t)(hf * 64) * lda + ks * 64,
                  ldsAw + (kt & 1) * ABYTES + hf * 64 * 128);
  };
  auto stBh = [&](int kt, int hf) {  // one B half (2 instr)
    int ks = kt < nk ? kt : nk - 1;
#pragma unroll
    for (int l = 0; l < 2; ++l)
      gload_lds16(Bs + (size_t)(hf * 128 + l * 64) * ldb + ks * 64,
                  ldsBw + (kt & 1) * BBYTES + hf * 128 * 128 + l * 8192);
  };

  const int fr = lane & 15, kq = lane >> 4;
  const int rA = wr * 64 + fr;
  const int rB = wc * 64 + fr;
  unsigned aof[2], bof[2];
  aof[0] = rA * 128 + ((kq ^ (rA & 7)) << 4);
  aof[1] = rA * 128 + (((kq + 4) ^ (rA & 7)) << 4);
  bof[0] = 2 * ABYTES + rB * 128 + ((kq ^ (rB & 7)) << 4);
  bof[1] = 2 * ABYTES + rB * 128 + (((kq + 4) ^ (rB & 7)) << 4);
  constexpr int A0 = 0, A1 = ABYTES, B0 = 0, B1 = BBYTES;

  f32x4 acc[4][4];
#pragma unroll
  for (int m = 0; m < 4; ++m)
#pragma unroll
    for (int n = 0; n < 4; ++n) acc[m][n] = (f32x4){0.f, 0.f, 0.f, 0.f};

  bf16x8 a[QM][2], b0[2][2], b1[2][2];

  // prologue: tile0 (6) + A(1)+B(1)h0 (4); vmcnt(4) drains tile0
  stA2(0); stBh(0, 0); stBh(0, 1);
  stA2(1); stBh(1, 0);
  asm volatile("s_waitcnt vmcnt(4)" ::: "memory");
  BAR();

  // WAR: buf1-Bh1 <- ph1 (read prev ph4) | buf0-A,Bh0 <- ph2 (ph1) |
  //      buf0-Bh1 <- ph3 (ph2) | buf1-A,Bh0 <- ph4 (ph3).
  // Gates: ph2 vmcnt(4) keeps [A(ka),B(ka)h0] -> tile(2t+1) landed before ph3;
  //        ph4 vmcnt(4) keeps [A(kb),B(kb)h0] -> tile(ka) landed before ph1'.
  for (int t = 0; t < niter; ++t) {
    const int ka = 2 * t + 2, kb = 2 * t + 3;
    // ph1: 12 reads (a+b0, buf0); stage B(2t+1)h1
    LDA8(a, 0, A0); LDB8(b0, 0, B0);
    stBh(2 * t + 1, 1);
    BAR(); LGKM0(); PRIO1(); MMQ(a, b0, 0, 0); PRIO0(); BAR();
    // ph2: 4 reads (b1); stage A(ka)+B(ka)h0; GATE
    LDB8(b1, 1, B0);
    stA2(ka); stBh(ka, 0);
    asm volatile("s_waitcnt vmcnt(4)" ::: "memory");
    BAR(); LGKM0(); PRIO1(); MMQ(a, b1, 0, 1); PRIO0(); BAR();
    // ph3: 12 reads (a+b0, buf1); stage B(ka)h1
    LDA8(a, 0, A1); LDB8(b0, 0, B1);
    stBh(ka, 1);
    BAR(); LGKM0(); PRIO1(); MMQ(a, b0, 0, 0); PRIO0(); BAR();
    // ph4: 4 reads (b1); stage A(kb)+B(kb)h0; GATE
    LDB8(b1, 1, B1);
    stA2(kb); stBh(kb, 0);
    asm volatile("s_waitcnt vmcnt(4)" ::: "memory");
    BAR(); LGKM0(); PRIO1(); MMQ(a, b1, 0, 1); PRIO0(); BAR();
  }
  EPILOGUE(4, 64)
}

// ---------------- row softmax, bf16 scores -> bf16 P in place ----------------
template <bool CAUSAL>
__global__ __launch_bounds__(256) void k_softmax(unsigned short* __restrict__ scores) {
  int row = blockIdx.x;  // b*S + i
  int i = row & (Ss - 1);
  unsigned short* src = scores + (size_t)row * Ss;
  int nv = CAUSAL ? i + 1 : Ss;
  int nb = CAUSAL ? ((i & ~127) + 128) : Ss;
  int t = threadIdx.x;
  int w = t >> 6, lane = t & 63;
  bool act = t * 8 < nb;
  float v[8];
  float mx = -1e30f;
  if (act) {
    u16x8 raw = *(const u16x8*)(src + t * 8);
#pragma unroll
    for (int k = 0; k < 8; k++) {
      int j = t * 8 + k;
      v[k] = (j < nv) ? bf2f(raw[k]) : -1e30f;
      mx = fmaxf(mx, v[k]);
    }
  } else {
#pragma unroll
    for (int k = 0; k < 8; k++) v[k] = -1e30f;
  }
#pragma unroll
  for (int o = 32; o; o >>= 1) mx = fmaxf(mx, __shfl_xor(mx, o));
  __shared__ float red[8];
  if (lane == 0) red[w] = mx;
  __syncthreads();
  mx = fmaxf(fmaxf(red[0], red[1]), fmaxf(red[2], red[3]));
  float sum = 0.f;
#pragma unroll
  for (int k = 0; k < 8; k++) {
    float e = (v[k] > -1e29f) ? __expf(v[k] - mx) : 0.f;
    v[k] = e;
    sum += e;
  }
#pragma unroll
  for (int o = 32; o; o >>= 1) sum += __shfl_xor(sum, o);
  if (lane == 0) red[4 + w] = sum;
  __syncthreads();
  sum = red[4] + red[5] + red[6] + red[7];
  float inv = 1.f / sum;
  if (act) {
    u16x8 r;
#pragma unroll
    for (int k = 0; k < 8; k++) r[k] = f2bf(v[k] * inv);
    *(u16x8*)(src + t * 8) = r;
  }
}

// ---------------- LayerNorm (input already has residual added) ----------------
__global__ __launch_bounds__(256) void k_ln(const float* __restrict__ a,
                                            const float* __restrict__ g,
                                            const float* __restrict__ be,
                                            float* __restrict__ outf,
                                            unsigned short* __restrict__ outb) {
  int row = blockIdx.x;
  size_t o = (size_t)row * Dd;
  int t = threadIdx.x;
  f32x4 x = *(const f32x4*)(a + o + t * 4);
  float s = x[0] + x[1] + x[2] + x[3];
  float q = x[0] * x[0] + x[1] * x[1] + x[2] * x[2] + x[3] * x[3];
  int w = t >> 6, lane = t & 63;
#pragma unroll
  for (int of = 32; of; of >>= 1) {
    s += __shfl_xor(s, of);
    q += __shfl_xor(q, of);
  }
  __shared__ float red[8];
  if (lane == 0) {
    red[w] = s;
    red[4 + w] = q;
  }
  __syncthreads();
  s = red[0] + red[1] + red[2] + red[3];
  q = red[4] + red[5] + red[6] + red[7];
  float mean = s * (1.f / Dd);
  float var = q * (1.f / Dd) - mean * mean;
  float rstd = rsqrtf(var + 1e-5f);
  f32x4 gv = *(const f32x4*)(g + t * 4);
  f32x4 bv = *(const f32x4*)(be + t * 4);
  f32x4 y;
#pragma unroll
  for (int k = 0; k < 4; k++) y[k] = (x[k] - mean) * rstd * gv[k] + bv[k];
  *(f32x4*)(outf + o + t * 4) = y;
  if (outb) {
    u16x4 r;
    r[0] = f2bf(y[0]); r[1] = f2bf(y[1]); r[2] = f2bf(y[2]); r[3] = f2bf(y[3]);
    *(u16x4*)(outb + o + t * 4) = r;
  }
}

extern "C" void kernel_launch(void* const* d_in, const int* in_sizes, int n_in, void* d_out,
                              int out_size, void* d_ws, size_t ws_size, hipStream_t stream) {
  (void)in_sizes; (void)n_in; (void)out_size; (void)ws_size;
  const float* y   = (const float*)d_in[0];
  const float* Z   = (const float*)d_in[1];
  const float* w1  = (const float*)d_in[2];
  const float* b1  = (const float*)d_in[3];
  const float* w2  = (const float*)d_in[4];
  const float* b2  = (const float*)d_in[5];
  const float* g1  = (const float*)d_in[6];
  const float* be1 = (const float*)d_in[7];
  const float* g2  = (const float*)d_in[8];
  const float* be2 = (const float*)d_in[9];
  const float* g3  = (const float*)d_in[10];
  const float* be3 = (const float*)d_in[11];
  float* out = (float*)d_out;

  char* ws = (char*)d_ws;
  const size_t MB = 1024ull * 1024ull;
  unsigned short* T   = (unsigned short*)(ws);            // y^T then Z^T (bf16)
  unsigned short* Zbf = (unsigned short*)(ws + 16 * MB);  // Z bf16
  unsigned short* ybf = (unsigned short*)(ws + 32 * MB);  // y / y1 / y2 bf16
  unsigned short* w1t = (unsigned short*)(ws + 48 * MB);  // w1^T bf16
  unsigned short* w2t = (unsigned short*)(ws + 56 * MB);  // w2^T bf16
  unsigned short* sc  = (unsigned short*)(ws + 64 * MB);  // scores/P bf16 (32MB)
  unsigned short* h   = (unsigned short*)(ws + 64 * MB);  // h bf16 (64MB) aliases dead sc
  float* res          = (float*)(ws + 128 * MB);          // residual stream fp32
  float* attn         = (float*)d_out;                    // attn / ff scratch

  dim3 b256(256), b512(512);
  const float scl = 1.f / 32.f;

  // --- self-attention ---
  k_transpose_cast<<<dim3(Dd / 32, Ss / 32, Bb), dim3(32, 8), 0, stream>>>(y, T, ybf, Ss, Dd);
  k_gemm8<0, true><<<dim3(36, 1, Bb), b512, 0, stream>>>(
      ybf, ybf, nullptr, sc, nullptr, nullptr, Dd, Dd, Dd, Ss,
      (long)Ss * Dd, (long)Ss * Dd, (long)Ss * Ss, scl);
  k_softmax<true><<<dim3(Bb * Ss), b256, 0, stream>>>(sc);
  k_gemm4<4, true><<<dim3(Dd / 256, Ss / 128, Bb), b512, 0, stream>>>(
      sc, T, attn, nullptr, nullptr, y, Ss, Ss, Ss, Dd,
      (long)Ss * Ss, (long)Dd * Ss, (long)Ss * Dd, 1.f);
  k_ln<<<dim3(Bb * Ss), b256, 0, stream>>>(attn, g1, be1, res, ybf);

  // --- cross-attention ---
  k_transpose_cast<<<dim3(Dd / 32, Ss / 32, Bb), dim3(32, 8), 0, stream>>>(Z, T, Zbf, Ss, Dd);
  k_gemm8<0, false><<<dim3(Ss / 256, Ss / 256, Bb), b512, 0, stream>>>(
      ybf, Zbf, nullptr, sc, nullptr, nullptr, Dd, Dd, Dd, Ss,
      (long)Ss * Dd, (long)Ss * Dd, (long)Ss * Ss, scl);
  k_softmax<false><<<dim3(Bb * Ss), b256, 0, stream>>>(sc);
  k_gemm4<4, false><<<dim3(Dd / 256, Ss / 128, Bb), b512, 0, stream>>>(
      sc, T, attn, nullptr, nullptr, res, Ss, Ss, Ss, Dd,
      (long)Ss * Ss, (long)Dd * Ss, (long)Ss * Dd, 1.f);
  k_ln<<<dim3(Bb * Ss), b256, 0, stream>>>(attn, g2, be2, res, ybf);

  // --- FFN ---
  k_transpose_cast<<<dim3(Ff / 32, Dd / 32, 1), dim3(32, 8), 0, stream>>>(w1, w1t, nullptr, Dd, Ff);
  k_transpose_cast<<<dim3(Dd / 32, Ff / 32, 1), dim3(32, 8), 0, stream>>>(w2, w2t, nullptr, Ff, Dd);
  k_gemm8<2, false><<<dim3(Ff / 256, (Bb * Ss) / 256, 1), b512, 0, stream>>>(
      ybf, w1t, nullptr, h, b1, nullptr, Dd, Dd, Dd, Ff, 0L, 0L, 0L, 1.f);
  k_gemm4<5, false><<<dim3(Dd / 256, (Bb * Ss) / 128, 1), b512, 0, stream>>>(
      h, w2t, attn, nullptr, b2, res, Ff, Ff, Ff, Dd, 0L, 0L, 0L, 1.f);
  k_ln<<<dim3(Bb * Ss), b256, 0, stream>>>(attn, g3, be3, out, nullptr);
}